// Round 18
// baseline (360.030 us; speedup 1.0000x reference)
//
#include <hip/hip_runtime.h>
#include <math.h>

// UniMP / TransformerConv x4 (heads=1), N=50000, E=1e6, D=64.
// R22b: resubmit of R22 (container infra failure, no counters) with a
//      defensive bound in bucketB (col write only if slot < E) -- converts
//      any unforeseen record-range hole from GPU-wedging OOB to wrong-answer.
//      Design: bucketed scatter. R21's null proved the scatter cost is
//      random-LINE write amplification (1e6 random 4B writes -> 1e6 line
//      touches, 58MB hbm at 1.2TB/s). Slots are a permutation of 0..E-1, so
//      bucket b = slot>>13 holds exactly 8192 slots:
//        bucketA: compute slot (same formula as R21 -> bit-identical col),
//                 LDS bucket-count, one global atomicAdd per (block,bucket),
//                 write (slot,src<<7) records into reserved contiguous runs.
//        bucketB: per bucket, coalesced record read + col writes inside a
//                 32KB L2-resident window (full line coverage).
//      gemm/attn/CSR-rest identical to R21 (absmax 0.1171875).

#define DD 64
#define NB_HIST 128
#define CHUNK_SHIFT 13            // 8192 edges/slots per chunk/bucket

typedef __attribute__((ext_vector_type(8))) _Float16 h8;   // 8 f16 (4 VGPR)
typedef __attribute__((ext_vector_type(2))) _Float16 h2;
typedef __attribute__((ext_vector_type(4))) float f32x4;
typedef __attribute__((ext_vector_type(2))) float f32x2;

#define QSCALE 0.18033688f   // (1/8) * log2(e): folded into Wq,bq at prep

__device__ __forceinline__ unsigned short f2h(float f) {
    union { _Float16 h; unsigned short u; } c;
    c.h = (_Float16)f;
    return c.u;
}
__device__ __forceinline__ h2 u2h2(unsigned u) {
    union { unsigned u; h2 h; } c; c.u = u; return c.h;
}
__device__ __forceinline__ unsigned pk2u(float a, float b) {  // v_cvt_pkrtz_f16_f32
    union { decltype(__builtin_amdgcn_cvt_pkrtz(0.f, 0.f)) h; unsigned u; } c;
    c.h = __builtin_amdgcn_cvt_pkrtz(a, b);
    return c.u;
}

// ---------------- CSR build + prep (fused) ----------------
// LDS histogram per 8192-edge chunk; the atomicAdd return IS the local rank
// -> stored to rank[e] (u16). Prep tail (x->f16, weight transposes) rides on.
__global__ __launch_bounds__(1024) void hist_prep(
    const int* __restrict__ dst, unsigned* __restrict__ cb,
    unsigned short* __restrict__ rank, int E, int nbw,
    const float* __restrict__ x, unsigned short* __restrict__ hbf, int nD,
    const float* __restrict__ W0, const float* __restrict__ W1,
    const float* __restrict__ W2, const float* __restrict__ W3,
    const float* __restrict__ Wqs, const float* __restrict__ Wks,
    const float* __restrict__ Wvs, const float* __restrict__ Wss,
    unsigned short* __restrict__ Wt) {
    extern __shared__ unsigned hist[];          // nbw words
    int blk = blockIdx.x;
    for (int w = threadIdx.x; w < nbw; w += blockDim.x) hist[w] = 0;
    __syncthreads();
    int beg = blk << CHUNK_SHIFT;
    int end = min(E, beg + (1 << CHUNK_SHIFT));
    for (int e = beg + (int)threadIdx.x; e < end; e += blockDim.x) {
        int d = dst[e];
        unsigned sh = (unsigned)(d & 1) * 16u;
        unsigned old = atomicAdd(&hist[d >> 1], 1u << sh);
        rank[e] = (unsigned short)((old >> sh) & 0xffffu);
    }
    __syncthreads();
    unsigned* out = cb + (size_t)blk * nbw;
    for (int w = threadIdx.x; w < nbw; w += blockDim.x) out[w] = hist[w];

    // ---- prep tail (grid-stride over x-convert + weight transposes) ----
    int total = nD + 16 * 4096;
    int stride = gridDim.x * blockDim.x;
    for (int i = blk * blockDim.x + threadIdx.x; i < total; i += stride) {
        if (i < nD) { hbf[i] = f2h(x[i]); continue; }
        int id = i - nD;
        int mat = id >> 12, rem = id & 4095;
        int nn = rem >> 6, kk = rem & 63;
        int layer = mat >> 2, wh = mat & 3;
        const float* W;
        if (layer == 0) W = wh == 0 ? W0 : wh == 1 ? W1 : wh == 2 ? W2 : W3;
        else {
            const float* base = wh == 0 ? Wqs : wh == 1 ? Wks : wh == 2 ? Wvs : Wss;
            W = base + (size_t)(layer - 1) * 4096;
        }
        float val = W[kk * 64 + nn];
        if (wh == 0) val *= QSCALE;       // fold 1/sqrt(64)*log2(e) into Wq
        Wt[id] = f2h(val);                // Wt[mat][n][k]
    }
}

// 16-wide register batches; NB_HIST=128 -> 8 serial rounds.
__global__ __launch_bounds__(256) void prefix_blk(unsigned* __restrict__ cb,
                                                  int* __restrict__ counts,
                                                  int nbw, int n) {
    int w = blockIdx.x * blockDim.x + threadIdx.x;
    if (w >= nbw) return;
    unsigned acc = 0;
#pragma unroll 1
    for (int c = 0; c < NB_HIST; c += 16) {
        unsigned t[16];
#pragma unroll
        for (int j = 0; j < 16; ++j) t[j] = cb[(size_t)(c + j) * nbw + w];
#pragma unroll
        for (int j = 0; j < 16; ++j) {
            unsigned v = t[j];
            cb[(size_t)(c + j) * nbw + w] = acc;   // exclusive prefix (packed)
            acc += v;                              // halves independent (<65536)
        }
    }
    counts[2 * w] = (int)(acc & 0xffffu);
    int b1 = 2 * w + 1;
    if (b1 < n) counts[b1] = (int)(acc >> 16);
}

__global__ __launch_bounds__(1024) void scan_local(const int* __restrict__ counts,
                                                   int* __restrict__ localscan,
                                                   int* __restrict__ blockSums, int n) {
    __shared__ int sh[1024];
    int i = blockIdx.x * 1024 + threadIdx.x;
    int val = (i < n) ? counts[i] : 0;
    sh[threadIdx.x] = val;
    __syncthreads();
    for (int off = 1; off < 1024; off <<= 1) {
        int t = (threadIdx.x >= off) ? sh[threadIdx.x - off] : 0;
        __syncthreads();
        sh[threadIdx.x] += t;
        __syncthreads();
    }
    if (i < n) localscan[i] = sh[threadIdx.x] - val;
    if (threadIdx.x == 1023) blockSums[blockIdx.x] = sh[1023];
}

// single-WAVE exclusive scan of block sums (nb <= 64; n=50000 -> 49)
__global__ __launch_bounds__(64) void scan_tops(int* __restrict__ blockSums, int nb) {
    int i = threadIdx.x;
    int val = (i < nb) ? blockSums[i] : 0;
    int s = val;
#pragma unroll
    for (int off = 1; off < 64; off <<= 1) {
        int t = __shfl_up(s, off, 64);
        if (i >= off) s += t;
    }
    if (i < nb) blockSums[i] = s - val;   // exclusive
}

// also initializes the bucket cursors: gcur[b] = b * 8192 (record base).
__global__ void emit_rowptr(const int* __restrict__ localscan,
                            const int* __restrict__ blockSums,
                            int* __restrict__ row_ptr,
                            unsigned* __restrict__ gcur, int n, int E) {
    int i = blockIdx.x * blockDim.x + threadIdx.x;
    if (i < n) row_ptr[i] = localscan[i] + blockSums[i >> 10];
    if (i == 0) row_ptr[n] = E;
    if (i < 128) gcur[i] = (unsigned)(i << CHUNK_SHIFT);
}

// ---- bucketed scatter pass A: (slot, src<<7) records grouped by slot>>13 ----
__global__ __launch_bounds__(1024) void bucketA(
    const int* __restrict__ src, const int* __restrict__ dst,
    const unsigned* __restrict__ cb, const unsigned short* __restrict__ rank,
    const int* __restrict__ row_ptr, unsigned* __restrict__ gcur,
    uint2* __restrict__ rec, int E, int nbw) {
    __shared__ unsigned cnt[128];
    __shared__ unsigned base[128];
    int tid = threadIdx.x;
    if (tid < 128) cnt[tid] = 0;
    __syncthreads();
    int beg = blockIdx.x << CHUNK_SHIFT;
    int slotv[8], srcv[8], bv[8];
#pragma unroll
    for (int j = 0; j < 8; ++j) {
        int e = beg + tid + (j << 10);
        bv[j] = -1;
        if (e < E) {
            int d = dst[e];
            unsigned sh = (unsigned)(d & 1) * 16u;
            unsigned pre = (cb[(size_t)blockIdx.x * nbw + (d >> 1)] >> sh) & 0xffffu;
            int slot = row_ptr[d] + (int)pre + (int)rank[e];
            slotv[j] = slot;
            srcv[j] = src[e] << 7;        // byte offset of 128B fp8 kv row
            int b = slot >> CHUNK_SHIFT;
            bv[j] = b;
            atomicAdd(&cnt[b], 1u);
        }
    }
    __syncthreads();
    if (tid < 128) {
        unsigned c = cnt[tid];
        base[tid] = c ? atomicAdd(&gcur[tid], c) : 0u;
        cnt[tid] = 0;
    }
    __syncthreads();
#pragma unroll
    for (int j = 0; j < 8; ++j) {
        if (bv[j] >= 0) {
            unsigned p = base[bv[j]] + atomicAdd(&cnt[bv[j]], 1u);
            uint2 r; r.x = (unsigned)slotv[j]; r.y = (unsigned)srcv[j];
            rec[p] = r;
        }
    }
}

// ---- pass B: per bucket, coalesced record read + L2-local col writes ----
__global__ __launch_bounds__(1024) void bucketB(const uint2* __restrict__ rec,
                                                int* __restrict__ col, int E) {
    int i = (blockIdx.x << CHUNK_SHIFT) + threadIdx.x;
#pragma unroll
    for (int j = 0; j < 8; ++j) {
        if (i < E) {
            uint2 r = rec[i];
            if (r.x < (unsigned)E)        // defensive: slot must be in range
                col[r.x] = (int)r.y;      // slot within 32KB window
        }
        i += 1024;
    }
}

// ---------------- MFMA projection ----------------
// Block = 4 waves; wave 0..3 -> Q,K,V,S. A = W (frags resident), B = h.
// wave0: f16 q (pre-scaled by QSCALE). wave1/2: fp8-e4m3 into byte-
// interleaved 128B kv row (chunk c = k[c*8..+8] | v[c*8..+8] at byte c*16).
// wave3: skip + residual (read from f16 hbf), stored f16 into sb.
__global__ __launch_bounds__(256) void gemm_mfma(
    const unsigned short* __restrict__ hbf, const unsigned short* __restrict__ Wt,
    const float* __restrict__ Bq, const float* __restrict__ Bk,
    const float* __restrict__ Bv, const float* __restrict__ Bs,
    int with_res,
    unsigned short* __restrict__ qO, unsigned char* __restrict__ kvO,
    unsigned short* __restrict__ sO, int ntiles) {
    int lane = threadIdx.x & 63;
    int wave = threadIdx.x >> 6;
    int ml = lane & 15, ql = lane >> 4;

    const unsigned short* W = Wt + wave * 4096;
    h8 wfrag[4][2];     // A-frag: A[m=ml][k=ql*8+j] = Wt[t*16+ml][kh*32+ql*8+j]
#pragma unroll
    for (int t = 0; t < 4; ++t)
#pragma unroll
        for (int kh = 0; kh < 2; ++kh)
            wfrag[t][kh] = *(const h8*)(W + (t * 16 + ml) * 64 + kh * 32 + ql * 8);

    const float* bias = wave == 0 ? Bq : wave == 1 ? Bk : wave == 2 ? Bv : Bs;
    float4 bias4[4];
#pragma unroll
    for (int t = 0; t < 4; ++t) {
        bias4[t] = *(const float4*)(bias + t * 16 + ql * 4);
        if (wave == 0) {
            bias4[t].x *= QSCALE; bias4[t].y *= QSCALE;
            bias4[t].z *= QSCALE; bias4[t].w *= QSCALE;
        }
    }

    for (int tile = blockIdx.x; tile < ntiles; tile += gridDim.x) {
        int node0 = tile * 16;           // n = 50000 = 3125 * 16, no partial tile
        h8 hfrag[2];                     // B-frag: B[k=ql*8+j][n=ml]
#pragma unroll
        for (int kh = 0; kh < 2; ++kh)
            hfrag[kh] = *(const h8*)(hbf + (size_t)(node0 + ml) * 64 + kh * 32 + ql * 8);
        f32x4 acc[4];
#pragma unroll
        for (int t = 0; t < 4; ++t) {
            acc[t][0] = bias4[t].x; acc[t][1] = bias4[t].y;
            acc[t][2] = bias4[t].z; acc[t][3] = bias4[t].w;
        }
#pragma unroll
        for (int t = 0; t < 4; ++t)
#pragma unroll
            for (int kh = 0; kh < 2; ++kh)
                acc[t] = __builtin_amdgcn_mfma_f32_16x16x32_f16(
                    wfrag[t][kh], hfrag[kh], acc[t], 0, 0, 0);

        size_t rowe = (size_t)(node0 + ml) * 64;
        if (wave == 0) {
#pragma unroll
            for (int t = 0; t < 4; ++t) {
                uint2 st;
                st.x = pk2u(acc[t][0], acc[t][1]);
                st.y = pk2u(acc[t][2], acc[t][3]);
                *(uint2*)(qO + rowe + t * 16 + ql * 4) = st;
            }
        } else if (wave == 3) {
#pragma unroll
            for (int t = 0; t < 4; ++t) {
                float4 st = {acc[t][0], acc[t][1], acc[t][2], acc[t][3]};
                if (with_res) {
                    uint2 hv = *(const uint2*)(hbf + rowe + t * 16 + ql * 4);
                    h2 r0 = u2h2(hv.x), r1 = u2h2(hv.y);
                    st.x += (float)r0[0]; st.y += (float)r0[1];
                    st.z += (float)r1[0]; st.w += (float)r1[1];
                }
                uint2 sp;
                sp.x = pk2u(st.x, st.y);
                sp.y = pk2u(st.z, st.w);
                *(uint2*)(sO + rowe + t * 16 + ql * 4) = sp;
            }
        } else {
            // dims [t*16+ql*4, +4) -> chunk = t*2 + (ql>>1), byte (ql&1)*4
            size_t kvr = (size_t)(node0 + ml) * 128 + (wave == 2 ? 8 : 0);
#pragma unroll
            for (int t = 0; t < 4; ++t) {
                int pk = __builtin_amdgcn_cvt_pk_fp8_f32(acc[t][0], acc[t][1], 0, false);
                pk = __builtin_amdgcn_cvt_pk_fp8_f32(acc[t][2], acc[t][3], pk, true);
                size_t addr = kvr + (size_t)(t * 2 + (ql >> 1)) * 16 + (ql & 1) * 4;
                *(unsigned*)(kvO + addr) = (unsigned)pk;
            }
        }
    }
}

// ---------------- fused attention + LN ----------------
// One wave per dst node; 8 groups of 8 lanes; x2 volley (16 edge-slots).
// Byte-interleaved fp8 kv row: lane qi reads ONE uint4 (k-chunk | v-chunk).
// Logits carry log2(e) pre-scale -> p = exp2f(d). fp32 accum, LN+ReLU.
#define EDGE_COMP(U) do {                                                      \
    f32x2 k0 = __builtin_amdgcn_cvt_pk_f32_fp8((U).x, false);                  \
    f32x2 k1 = __builtin_amdgcn_cvt_pk_f32_fp8((U).x, true);                   \
    f32x2 k2 = __builtin_amdgcn_cvt_pk_f32_fp8((U).y, false);                  \
    f32x2 k3 = __builtin_amdgcn_cvt_pk_f32_fp8((U).y, true);                   \
    float d = qf0 * k0[0];                                                     \
    d = fmaf(qf1, k0[1], d); d = fmaf(qf2, k1[0], d); d = fmaf(qf3, k1[1], d); \
    d = fmaf(qf4, k2[0], d); d = fmaf(qf5, k2[1], d); d = fmaf(qf6, k3[0], d); \
    d = fmaf(qf7, k3[1], d);                                                   \
    d += __shfl_xor(d, 1); d += __shfl_xor(d, 2); d += __shfl_xor(d, 4);       \
    float p = exp2f(d); ssum += p;                                             \
    f32x2 w0 = __builtin_amdgcn_cvt_pk_f32_fp8((U).z, false);                  \
    f32x2 w1 = __builtin_amdgcn_cvt_pk_f32_fp8((U).z, true);                   \
    f32x2 w2 = __builtin_amdgcn_cvt_pk_f32_fp8((U).w, false);                  \
    f32x2 w3 = __builtin_amdgcn_cvt_pk_f32_fp8((U).w, true);                   \
    aa.x = fmaf(w0[0], p, aa.x); aa.y = fmaf(w0[1], p, aa.y);                  \
    aa.z = fmaf(w1[0], p, aa.z); aa.w = fmaf(w1[1], p, aa.w);                  \
    ab.x = fmaf(w2[0], p, ab.x); ab.y = fmaf(w2[1], p, ab.y);                  \
    ab.z = fmaf(w3[0], p, ab.z); ab.w = fmaf(w3[1], p, ab.w);                  \
} while (0)

__global__ __launch_bounds__(256) void attn_agg_ln(
    const unsigned short* __restrict__ qh, const unsigned char* __restrict__ kv,
    const unsigned short* __restrict__ sk,
    const int* __restrict__ row_ptr, const int* __restrict__ col,
    const float* __restrict__ g, const float* __restrict__ b,
    float* __restrict__ out, unsigned short* __restrict__ hbf_out, int n) {
    int node = blockIdx.x * 4 + (threadIdx.x >> 6);
    int lane = threadIdx.x & 63;
    if (node >= n) return;
    int grp = lane >> 3;
    int qi = lane & 7;

    size_t ro = (size_t)node * DD + qi * 8;
    uint4 qu = *(const uint4*)(qh + ro);          // 8 f16, pre-scaled QSCALE
    uint4 su = *(const uint4*)(sk + ro);          // 8 f16 skip(+residual)
    int beg = row_ptr[node], end = row_ptr[node + 1];

    // unpack q to 8 f32 once (feeds fp8-k fma chain)
    h2 q0 = u2h2(qu.x), q1 = u2h2(qu.y), q2 = u2h2(qu.z), q3 = u2h2(qu.w);
    float qf0 = (float)q0[0], qf1 = (float)q0[1], qf2 = (float)q1[0], qf3 = (float)q1[1];
    float qf4 = (float)q2[0], qf5 = (float)q2[1], qf6 = (float)q3[0], qf7 = (float)q3[1];

    float ssum = 0.0f;
    float4 aa = {0.f, 0.f, 0.f, 0.f}, ab = {0.f, 0.f, 0.f, 0.f};

    int e = beg + grp;
    int cv0 = (e < end) ? col[e] : -1;
    int cv1 = (e + 8 < end) ? col[e + 8] : -1;
    for (int e0 = beg; e0 < end; e0 += 16) {
        bool a0 = cv0 >= 0, a1 = cv1 >= 0;
        uint4 u0, u1;
        if (a0) u0 = *(const uint4*)(kv + cv0 + qi * 16);   // k|v chunk, one load
        if (a1) u1 = *(const uint4*)(kv + cv1 + qi * 16);
        e += 16;
        cv0 = (e < end) ? col[e] : -1;
        cv1 = (e + 8 < end) ? col[e + 8] : -1;
        if (a0) EDGE_COMP(u0);
        if (a1) EDGE_COMP(u1);
    }

#pragma unroll
    for (int off = 8; off <= 32; off <<= 1) {
        ssum += __shfl_xor(ssum, off);
        aa.x += __shfl_xor(aa.x, off); aa.y += __shfl_xor(aa.y, off);
        aa.z += __shfl_xor(aa.z, off); aa.w += __shfl_xor(aa.w, off);
        ab.x += __shfl_xor(ab.x, off); ab.y += __shfl_xor(ab.y, off);
        ab.z += __shfl_xor(ab.z, off); ab.w += __shfl_xor(ab.w, off);
    }
    float inv = (end > beg) ? 1.0f / ssum : 0.0f;
    aa.x *= inv; aa.y *= inv; aa.z *= inv; aa.w *= inv;
    ab.x *= inv; ab.y *= inv; ab.z *= inv; ab.w *= inv;

    {   // + skip (+ residual), f16 -> f32
        h2 t0 = u2h2(su.x), t1 = u2h2(su.y), t2 = u2h2(su.z), t3 = u2h2(su.w);
        aa.x += (float)t0[0]; aa.y += (float)t0[1];
        aa.z += (float)t1[0]; aa.w += (float)t1[1];
        ab.x += (float)t2[0]; ab.y += (float)t2[1];
        ab.z += (float)t3[0]; ab.w += (float)t3[1];
    }

    float s1 = aa.x + aa.y + aa.z + aa.w + ab.x + ab.y + ab.z + ab.w;
    s1 += __shfl_xor(s1, 1);
    s1 += __shfl_xor(s1, 2);
    s1 += __shfl_xor(s1, 4);
    float mu = s1 * (1.0f / DD);
    float dx0 = aa.x - mu, dx1 = aa.y - mu, dx2 = aa.z - mu, dx3 = aa.w - mu;
    float dx4 = ab.x - mu, dx5 = ab.y - mu, dx6 = ab.z - mu, dx7 = ab.w - mu;
    float s2v = dx0 * dx0 + dx1 * dx1 + dx2 * dx2 + dx3 * dx3
              + dx4 * dx4 + dx5 * dx5 + dx6 * dx6 + dx7 * dx7;
    s2v += __shfl_xor(s2v, 1);
    s2v += __shfl_xor(s2v, 2);
    s2v += __shfl_xor(s2v, 4);
    float var = s2v * (1.0f / DD);
    float is = rsqrtf(var + 1e-5f);
    float4 g4a = *(const float4*)(g + qi * 8);
    float4 g4b = *(const float4*)(g + qi * 8 + 4);
    float4 b4a = *(const float4*)(b + qi * 8);
    float4 b4b = *(const float4*)(b + qi * 8 + 4);
    float4 ya, yb;
    ya.x = fmaxf(dx0 * is * g4a.x + b4a.x, 0.0f);
    ya.y = fmaxf(dx1 * is * g4a.y + b4a.y, 0.0f);
    ya.z = fmaxf(dx2 * is * g4a.z + b4a.z, 0.0f);
    ya.w = fmaxf(dx3 * is * g4a.w + b4a.w, 0.0f);
    yb.x = fmaxf(dx4 * is * g4b.x + b4b.x, 0.0f);
    yb.y = fmaxf(dx5 * is * g4b.y + b4b.y, 0.0f);
    yb.z = fmaxf(dx6 * is * g4b.z + b4b.z, 0.0f);
    yb.w = fmaxf(dx7 * is * g4b.w + b4b.w, 0.0f);
    if (grp == 0) {
        if (out) {
            *(float4*)(out + ro) = ya;
            *(float4*)(out + ro + 4) = yb;
        }
        uint4 hv;
        hv.x = pk2u(ya.x, ya.y);
        hv.y = pk2u(ya.z, ya.w);
        hv.z = pk2u(yb.x, yb.y);
        hv.w = pk2u(yb.z, yb.w);
        *(uint4*)(hbf_out + ro) = hv;
    }
}

extern "C" void kernel_launch(void* const* d_in, const int* in_sizes, int n_in,
                              void* d_out, int out_size, void* d_ws, size_t ws_size,
                              hipStream_t stream) {
    const int D = DD;
    const float* x = (const float*)d_in[0];
    const int n = in_sizes[0] / D;       // 50000
    const int* ei = (const int*)d_in[1];
    const int E = in_sizes[1] / 2;       // 1e6
    const int* srcp = ei;
    const int* dstp = ei + E;
    const int nbw = (n + 1) / 2;         // bin-pair words (25000)
    const int nchunk = (E + (1 << CHUNK_SHIFT) - 1) >> CHUNK_SHIFT;   // 123

    static bool s_attr = false;
    if (!s_attr) {
        s_attr = true;
        (void)hipFuncSetAttribute((const void*)hist_prep,
                                  hipFuncAttributeMaxDynamicSharedMemorySize, 102400);
    }

    char* wsp = (char*)d_ws;
    auto take = [&](size_t bytes) {
        char* p = wsp;
        wsp += (bytes + 255) & ~(size_t)255;
        return (void*)p;
    };
    int* counts    = (int*)take((size_t)n * 4);
    int* row_ptr   = (int*)take((size_t)(n + 1) * 4);
    unsigned* cb   = (unsigned*)take((size_t)NB_HIST * nbw * 4);   // 12.8 MB
    unsigned short* rankb = (unsigned short*)take((size_t)E * 2);  // u16 ranks
    unsigned* gcur = (unsigned*)take((size_t)128 * 4);
    uint2* rec     = (uint2*)take((size_t)E * 8);                  // 8 MB records
    int* col       = (int*)take((size_t)E * 4);
    int* localscan = (int*)take((size_t)n * 4);
    int* blockSums = (int*)take((size_t)1024 * 4);
    size_t fsz = (size_t)n * D * 4;
    unsigned short* qb  = (unsigned short*)take(fsz / 2);   // f16 q (pre-scaled)
    unsigned char* kvb  = (unsigned char*)take(fsz / 2);    // fp8 k|v rows: n*128B
    unsigned short* sb  = (unsigned short*)take(fsz / 2);   // f16 skip+residual
    unsigned short* hbf = (unsigned short*)take(fsz / 2);   // f16 h (layer carrier)
    unsigned short* Wt  = (unsigned short*)take((size_t)16 * 4096 * 2);

    // ---- CSR build + prep (no per-edge global atomics) ----
    int tb = 256;
    size_t ldsH = (size_t)nbw * 4;       // 100 KB
    int nbScan = (n + 1023) / 1024;
    hist_prep<<<NB_HIST, 1024, ldsH, stream>>>(
        dstp, cb, rankb, E, nbw,
        x, hbf, n * D,
        (const float*)d_in[2], (const float*)d_in[4], (const float*)d_in[6],
        (const float*)d_in[8], (const float*)d_in[12], (const float*)d_in[14],
        (const float*)d_in[16], (const float*)d_in[18], Wt);
    prefix_blk<<<(nbw + tb - 1) / tb, tb, 0, stream>>>(cb, counts, nbw, n);
    scan_local<<<nbScan, 1024, 0, stream>>>(counts, localscan, blockSums, n);
    scan_tops<<<1, 64, 0, stream>>>(blockSums, nbScan);
    emit_rowptr<<<(n + tb - 1) / tb, tb, 0, stream>>>(localscan, blockSums,
                                                      row_ptr, gcur, n, E);
    bucketA<<<nchunk, 1024, 0, stream>>>(srcp, dstp, cb, rankb, row_ptr,
                                         gcur, rec, E, nbw);
    bucketB<<<nchunk, 1024, 0, stream>>>(rec, col, E);

    // ---- 4 conv layers ----
    int ntiles = n / 16;                 // 3125
    int nba = (n + 3) / 4;
    for (int layer = 0; layer < 4; ++layer) {
        const float *bq_, *bk_, *bv_, *bs_, *g_, *b_;
        if (layer == 0) {
            bq_ = (const float*)d_in[3];  bk_ = (const float*)d_in[5];
            bv_ = (const float*)d_in[7];  bs_ = (const float*)d_in[9];
            g_  = (const float*)d_in[10]; b_  = (const float*)d_in[11];
        } else {
            int i = layer - 1;
            bq_ = (const float*)d_in[13] + (size_t)i * D;
            bk_ = (const float*)d_in[15] + (size_t)i * D;
            bv_ = (const float*)d_in[17] + (size_t)i * D;
            bs_ = (const float*)d_in[19] + (size_t)i * D;
            g_  = (const float*)d_in[20] + (size_t)i * D;
            b_  = (const float*)d_in[21] + (size_t)i * D;
        }
        gemm_mfma<<<512, 256, 0, stream>>>(hbf, Wt + (size_t)layer * 4 * 4096,
                                           bq_, bk_, bv_, bs_,
                                           layer == 0 ? 0 : 1,
                                           qb, kvb, sb, ntiles);
        attn_agg_ln<<<nba, 256, 0, stream>>>(qb, kvb, sb, row_ptr, col, g_, b_,
                                             layer == 3 ? (float*)d_out : nullptr,
                                             hbf, n);
    }
}

// Round 19
// 354.369 us; speedup vs baseline: 1.0160x; 1.0160x over previous
//
#include <hip/hip_runtime.h>
#include <math.h>

// UniMP / TransformerConv x4 (heads=1), N=50000, E=1e6, D=64.
// R23 = exact revert to R20, the session's best-measured kernel (353.1us).
//      Rationale: R21 (streaming scatter) and R22/R22b (bucketed scatter)
//      both failed to beat R20's scatter2 -- the scatter stage costs ~40-45us
//      in every formulation (random-line churn or its replacement costs), and
//      all other kernels sit below the profiler's top-5 cutoff. Five nulls/
//      regressions in the last six structural attempts => distributed plateau;
//      lock in the best configuration.
//      Stack: f16 MFMA gemm (W-frags resident, grid 512), fp8-e4m3 K/V in
//      byte-interleaved 128B rows, f16 q (QSCALE = 0.125*log2e folded) with
//      exp2 softmax, f16 sb/hbf carriers, LDS-histogram CSR (NB_HIST=128,
//      batched prefix), hist+prep fusion.

#define DD 64
#define NB_HIST 128

typedef __attribute__((ext_vector_type(8))) _Float16 h8;   // 8 f16 (4 VGPR)
typedef __attribute__((ext_vector_type(2))) _Float16 h2;
typedef __attribute__((ext_vector_type(4))) float f32x4;
typedef __attribute__((ext_vector_type(2))) float f32x2;

#define QSCALE 0.18033688f   // (1/8) * log2(e): folded into Wq,bq at prep

__device__ __forceinline__ unsigned short f2h(float f) {
    union { _Float16 h; unsigned short u; } c;
    c.h = (_Float16)f;
    return c.u;
}
__device__ __forceinline__ h2 u2h2(unsigned u) {
    union { unsigned u; h2 h; } c; c.u = u; return c.h;
}
__device__ __forceinline__ unsigned pk2u(float a, float b) {  // v_cvt_pkrtz_f16_f32
    union { decltype(__builtin_amdgcn_cvt_pkrtz(0.f, 0.f)) h; unsigned u; } c;
    c.h = __builtin_amdgcn_cvt_pkrtz(a, b);
    return c.u;
}

// ---------------- CSR build + prep (fused) ----------------
__global__ __launch_bounds__(1024) void hist_prep(
    const int* __restrict__ dst, unsigned* __restrict__ cb, int E, int nbw,
    const float* __restrict__ x, unsigned short* __restrict__ hbf, int nD,
    const float* __restrict__ W0, const float* __restrict__ W1,
    const float* __restrict__ W2, const float* __restrict__ W3,
    const float* __restrict__ Wqs, const float* __restrict__ Wks,
    const float* __restrict__ Wvs, const float* __restrict__ Wss,
    unsigned short* __restrict__ Wt) {
    extern __shared__ unsigned hist[];          // nbw words
    int blk = blockIdx.x;
    for (int w = threadIdx.x; w < nbw; w += blockDim.x) hist[w] = 0;
    __syncthreads();
    int chunk = (E + gridDim.x - 1) / gridDim.x;
    int beg = blk * chunk;
    int end = min(E, beg + chunk);
    for (int e = beg + (int)threadIdx.x; e < end; e += blockDim.x) {
        int d = dst[e];
        atomicAdd(&hist[d >> 1], (d & 1) ? 0x10000u : 1u);
    }
    __syncthreads();
    unsigned* out = cb + (size_t)blk * nbw;
    for (int w = threadIdx.x; w < nbw; w += blockDim.x) out[w] = hist[w];

    // ---- prep tail (grid-stride over x-convert + weight transposes) ----
    int total = nD + 16 * 4096;
    int stride = gridDim.x * blockDim.x;
    for (int i = blk * blockDim.x + threadIdx.x; i < total; i += stride) {
        if (i < nD) { hbf[i] = f2h(x[i]); continue; }
        int id = i - nD;
        int mat = id >> 12, rem = id & 4095;
        int nn = rem >> 6, kk = rem & 63;
        int layer = mat >> 2, wh = mat & 3;
        const float* W;
        if (layer == 0) W = wh == 0 ? W0 : wh == 1 ? W1 : wh == 2 ? W2 : W3;
        else {
            const float* base = wh == 0 ? Wqs : wh == 1 ? Wks : wh == 2 ? Wvs : Wss;
            W = base + (size_t)(layer - 1) * 4096;
        }
        float val = W[kk * 64 + nn];
        if (wh == 0) val *= QSCALE;       // fold 1/sqrt(64)*log2(e) into Wq
        Wt[id] = f2h(val);                // Wt[mat][n][k]
    }
}

// 16-wide register batches; NB_HIST=128 -> 8 serial rounds.
__global__ __launch_bounds__(256) void prefix_blk(unsigned* __restrict__ cb,
                                                  int* __restrict__ counts,
                                                  int nbw, int n) {
    int w = blockIdx.x * blockDim.x + threadIdx.x;
    if (w >= nbw) return;
    unsigned acc = 0;
#pragma unroll 1
    for (int c = 0; c < NB_HIST; c += 16) {
        unsigned t[16];
#pragma unroll
        for (int j = 0; j < 16; ++j) t[j] = cb[(size_t)(c + j) * nbw + w];
#pragma unroll
        for (int j = 0; j < 16; ++j) {
            unsigned v = t[j];
            cb[(size_t)(c + j) * nbw + w] = acc;   // exclusive prefix (packed)
            acc += v;                              // halves independent (<65536)
        }
    }
    counts[2 * w] = (int)(acc & 0xffffu);
    int b1 = 2 * w + 1;
    if (b1 < n) counts[b1] = (int)(acc >> 16);
}

__global__ __launch_bounds__(1024) void scan_local(const int* __restrict__ counts,
                                                   int* __restrict__ localscan,
                                                   int* __restrict__ blockSums, int n) {
    __shared__ int sh[1024];
    int i = blockIdx.x * 1024 + threadIdx.x;
    int val = (i < n) ? counts[i] : 0;
    sh[threadIdx.x] = val;
    __syncthreads();
    for (int off = 1; off < 1024; off <<= 1) {
        int t = (threadIdx.x >= off) ? sh[threadIdx.x - off] : 0;
        __syncthreads();
        sh[threadIdx.x] += t;
        __syncthreads();
    }
    if (i < n) localscan[i] = sh[threadIdx.x] - val;
    if (threadIdx.x == 1023) blockSums[blockIdx.x] = sh[1023];
}

// single-WAVE exclusive scan of block sums (nb <= 64; n=50000 -> 49)
__global__ __launch_bounds__(64) void scan_tops(int* __restrict__ blockSums, int nb) {
    int i = threadIdx.x;
    int val = (i < nb) ? blockSums[i] : 0;
    int s = val;
#pragma unroll
    for (int off = 1; off < 64; off <<= 1) {
        int t = __shfl_up(s, off, 64);
        if (i >= off) s += t;
    }
    if (i < nb) blockSums[i] = s - val;   // exclusive
}

__global__ void emit_rowptr(const int* __restrict__ localscan,
                            const int* __restrict__ blockSums,
                            int* __restrict__ row_ptr, int n, int E) {
    int i = blockIdx.x * blockDim.x + threadIdx.x;
    if (i < n) row_ptr[i] = localscan[i] + blockSums[i >> 10];
    if (i == 0) row_ptr[n] = E;
}

// col[] stores BYTE offset of the 128B fp8 kv row: src * 128.
__global__ __launch_bounds__(1024) void scatter2(const int* __restrict__ src,
                                                 const int* __restrict__ dst,
                                                 const unsigned* __restrict__ cb,
                                                 const int* __restrict__ row_ptr,
                                                 int* __restrict__ col, int E, int nbw) {
    extern __shared__ unsigned hist[];
    int blk = blockIdx.x;
    for (int w = threadIdx.x; w < nbw; w += blockDim.x) hist[w] = 0;
    __syncthreads();
    const unsigned* pref = cb + (size_t)blk * nbw;
    int chunk = (E + gridDim.x - 1) / gridDim.x;
    int beg = blk * chunk;
    int end = min(E, beg + chunk);
    for (int e = beg + (int)threadIdx.x; e < end; e += blockDim.x) {
        int d = dst[e];
        unsigned sh = (unsigned)(d & 1) * 16u;
        unsigned old = atomicAdd(&hist[d >> 1], 1u << sh);
        unsigned lr = (old >> sh) & 0xffffu;
        unsigned pre = (pref[d >> 1] >> sh) & 0xffffu;
        int slot = row_ptr[d] + (int)pre + (int)lr;
        __builtin_nontemporal_store(src[e] << 7, &col[slot]);
    }
}

// ---------------- MFMA projection ----------------
// Block = 4 waves; wave 0..3 -> Q,K,V,S. A = W (frags resident), B = h.
// wave0: f16 q (pre-scaled by QSCALE). wave1/2: fp8-e4m3 into byte-
// interleaved 128B kv row (chunk c = k[c*8..+8] | v[c*8..+8] at byte c*16).
// wave3: skip + residual (read from f16 hbf), stored f16 into sb.
__global__ __launch_bounds__(256) void gemm_mfma(
    const unsigned short* __restrict__ hbf, const unsigned short* __restrict__ Wt,
    const float* __restrict__ Bq, const float* __restrict__ Bk,
    const float* __restrict__ Bv, const float* __restrict__ Bs,
    int with_res,
    unsigned short* __restrict__ qO, unsigned char* __restrict__ kvO,
    unsigned short* __restrict__ sO, int ntiles) {
    int lane = threadIdx.x & 63;
    int wave = threadIdx.x >> 6;
    int ml = lane & 15, ql = lane >> 4;

    const unsigned short* W = Wt + wave * 4096;
    h8 wfrag[4][2];     // A-frag: A[m=ml][k=ql*8+j] = Wt[t*16+ml][kh*32+ql*8+j]
#pragma unroll
    for (int t = 0; t < 4; ++t)
#pragma unroll
        for (int kh = 0; kh < 2; ++kh)
            wfrag[t][kh] = *(const h8*)(W + (t * 16 + ml) * 64 + kh * 32 + ql * 8);

    const float* bias = wave == 0 ? Bq : wave == 1 ? Bk : wave == 2 ? Bv : Bs;
    float4 bias4[4];
#pragma unroll
    for (int t = 0; t < 4; ++t) {
        bias4[t] = *(const float4*)(bias + t * 16 + ql * 4);
        if (wave == 0) {
            bias4[t].x *= QSCALE; bias4[t].y *= QSCALE;
            bias4[t].z *= QSCALE; bias4[t].w *= QSCALE;
        }
    }

    for (int tile = blockIdx.x; tile < ntiles; tile += gridDim.x) {
        int node0 = tile * 16;           // n = 50000 = 3125 * 16, no partial tile
        h8 hfrag[2];                     // B-frag: B[k=ql*8+j][n=ml]
#pragma unroll
        for (int kh = 0; kh < 2; ++kh)
            hfrag[kh] = *(const h8*)(hbf + (size_t)(node0 + ml) * 64 + kh * 32 + ql * 8);
        f32x4 acc[4];
#pragma unroll
        for (int t = 0; t < 4; ++t) {
            acc[t][0] = bias4[t].x; acc[t][1] = bias4[t].y;
            acc[t][2] = bias4[t].z; acc[t][3] = bias4[t].w;
        }
#pragma unroll
        for (int t = 0; t < 4; ++t)
#pragma unroll
            for (int kh = 0; kh < 2; ++kh)
                acc[t] = __builtin_amdgcn_mfma_f32_16x16x32_f16(
                    wfrag[t][kh], hfrag[kh], acc[t], 0, 0, 0);

        size_t rowe = (size_t)(node0 + ml) * 64;
        if (wave == 0) {
#pragma unroll
            for (int t = 0; t < 4; ++t) {
                uint2 st;
                st.x = pk2u(acc[t][0], acc[t][1]);
                st.y = pk2u(acc[t][2], acc[t][3]);
                *(uint2*)(qO + rowe + t * 16 + ql * 4) = st;
            }
        } else if (wave == 3) {
#pragma unroll
            for (int t = 0; t < 4; ++t) {
                float4 st = {acc[t][0], acc[t][1], acc[t][2], acc[t][3]};
                if (with_res) {
                    uint2 hv = *(const uint2*)(hbf + rowe + t * 16 + ql * 4);
                    h2 r0 = u2h2(hv.x), r1 = u2h2(hv.y);
                    st.x += (float)r0[0]; st.y += (float)r0[1];
                    st.z += (float)r1[0]; st.w += (float)r1[1];
                }
                uint2 sp;
                sp.x = pk2u(st.x, st.y);
                sp.y = pk2u(st.z, st.w);
                *(uint2*)(sO + rowe + t * 16 + ql * 4) = sp;
            }
        } else {
            // dims [t*16+ql*4, +4) -> chunk = t*2 + (ql>>1), byte (ql&1)*4
            size_t kvr = (size_t)(node0 + ml) * 128 + (wave == 2 ? 8 : 0);
#pragma unroll
            for (int t = 0; t < 4; ++t) {
                int pk = __builtin_amdgcn_cvt_pk_fp8_f32(acc[t][0], acc[t][1], 0, false);
                pk = __builtin_amdgcn_cvt_pk_fp8_f32(acc[t][2], acc[t][3], pk, true);
                size_t addr = kvr + (size_t)(t * 2 + (ql >> 1)) * 16 + (ql & 1) * 4;
                *(unsigned*)(kvO + addr) = (unsigned)pk;
            }
        }
    }
}

// ---------------- fused attention + LN ----------------
// One wave per dst node; 8 groups of 8 lanes; x2 volley (16 edge-slots).
// Byte-interleaved fp8 kv row: lane qi reads ONE uint4 (k-chunk | v-chunk).
// Logits carry log2(e) pre-scale -> p = exp2f(d). fp32 accum, LN+ReLU.
#define EDGE_COMP(U) do {                                                      \
    f32x2 k0 = __builtin_amdgcn_cvt_pk_f32_fp8((U).x, false);                  \
    f32x2 k1 = __builtin_amdgcn_cvt_pk_f32_fp8((U).x, true);                   \
    f32x2 k2 = __builtin_amdgcn_cvt_pk_f32_fp8((U).y, false);                  \
    f32x2 k3 = __builtin_amdgcn_cvt_pk_f32_fp8((U).y, true);                   \
    float d = qf0 * k0[0];                                                     \
    d = fmaf(qf1, k0[1], d); d = fmaf(qf2, k1[0], d); d = fmaf(qf3, k1[1], d); \
    d = fmaf(qf4, k2[0], d); d = fmaf(qf5, k2[1], d); d = fmaf(qf6, k3[0], d); \
    d = fmaf(qf7, k3[1], d);                                                   \
    d += __shfl_xor(d, 1); d += __shfl_xor(d, 2); d += __shfl_xor(d, 4);       \
    float p = exp2f(d); ssum += p;                                             \
    f32x2 w0 = __builtin_amdgcn_cvt_pk_f32_fp8((U).z, false);                  \
    f32x2 w1 = __builtin_amdgcn_cvt_pk_f32_fp8((U).z, true);                   \
    f32x2 w2 = __builtin_amdgcn_cvt_pk_f32_fp8((U).w, false);                  \
    f32x2 w3 = __builtin_amdgcn_cvt_pk_f32_fp8((U).w, true);                   \
    aa.x = fmaf(w0[0], p, aa.x); aa.y = fmaf(w0[1], p, aa.y);                  \
    aa.z = fmaf(w1[0], p, aa.z); aa.w = fmaf(w1[1], p, aa.w);                  \
    ab.x = fmaf(w2[0], p, ab.x); ab.y = fmaf(w2[1], p, ab.y);                  \
    ab.z = fmaf(w3[0], p, ab.z); ab.w = fmaf(w3[1], p, ab.w);                  \
} while (0)

__global__ __launch_bounds__(256) void attn_agg_ln(
    const unsigned short* __restrict__ qh, const unsigned char* __restrict__ kv,
    const unsigned short* __restrict__ sk,
    const int* __restrict__ row_ptr, const int* __restrict__ col,
    const float* __restrict__ g, const float* __restrict__ b,
    float* __restrict__ out, unsigned short* __restrict__ hbf_out, int n) {
    int node = blockIdx.x * 4 + (threadIdx.x >> 6);
    int lane = threadIdx.x & 63;
    if (node >= n) return;
    int grp = lane >> 3;
    int qi = lane & 7;

    size_t ro = (size_t)node * DD + qi * 8;
    uint4 qu = *(const uint4*)(qh + ro);          // 8 f16, pre-scaled QSCALE
    uint4 su = *(const uint4*)(sk + ro);          // 8 f16 skip(+residual)
    int beg = row_ptr[node], end = row_ptr[node + 1];

    // unpack q to 8 f32 once (feeds fp8-k fma chain)
    h2 q0 = u2h2(qu.x), q1 = u2h2(qu.y), q2 = u2h2(qu.z), q3 = u2h2(qu.w);
    float qf0 = (float)q0[0], qf1 = (float)q0[1], qf2 = (float)q1[0], qf3 = (float)q1[1];
    float qf4 = (float)q2[0], qf5 = (float)q2[1], qf6 = (float)q3[0], qf7 = (float)q3[1];

    float ssum = 0.0f;
    float4 aa = {0.f, 0.f, 0.f, 0.f}, ab = {0.f, 0.f, 0.f, 0.f};

    int e = beg + grp;
    int cv0 = (e < end) ? col[e] : -1;
    int cv1 = (e + 8 < end) ? col[e + 8] : -1;
    for (int e0 = beg; e0 < end; e0 += 16) {
        bool a0 = cv0 >= 0, a1 = cv1 >= 0;
        uint4 u0, u1;
        if (a0) u0 = *(const uint4*)(kv + cv0 + qi * 16);   // k|v chunk, one load
        if (a1) u1 = *(const uint4*)(kv + cv1 + qi * 16);
        e += 16;
        cv0 = (e < end) ? col[e] : -1;
        cv1 = (e + 8 < end) ? col[e + 8] : -1;
        if (a0) EDGE_COMP(u0);
        if (a1) EDGE_COMP(u1);
    }

#pragma unroll
    for (int off = 8; off <= 32; off <<= 1) {
        ssum += __shfl_xor(ssum, off);
        aa.x += __shfl_xor(aa.x, off); aa.y += __shfl_xor(aa.y, off);
        aa.z += __shfl_xor(aa.z, off); aa.w += __shfl_xor(aa.w, off);
        ab.x += __shfl_xor(ab.x, off); ab.y += __shfl_xor(ab.y, off);
        ab.z += __shfl_xor(ab.z, off); ab.w += __shfl_xor(ab.w, off);
    }
    float inv = (end > beg) ? 1.0f / ssum : 0.0f;
    aa.x *= inv; aa.y *= inv; aa.z *= inv; aa.w *= inv;
    ab.x *= inv; ab.y *= inv; ab.z *= inv; ab.w *= inv;

    {   // + skip (+ residual), f16 -> f32
        h2 t0 = u2h2(su.x), t1 = u2h2(su.y), t2 = u2h2(su.z), t3 = u2h2(su.w);
        aa.x += (float)t0[0]; aa.y += (float)t0[1];
        aa.z += (float)t1[0]; aa.w += (float)t1[1];
        ab.x += (float)t2[0]; ab.y += (float)t2[1];
        ab.z += (float)t3[0]; ab.w += (float)t3[1];
    }

    float s1 = aa.x + aa.y + aa.z + aa.w + ab.x + ab.y + ab.z + ab.w;
    s1 += __shfl_xor(s1, 1);
    s1 += __shfl_xor(s1, 2);
    s1 += __shfl_xor(s1, 4);
    float mu = s1 * (1.0f / DD);
    float dx0 = aa.x - mu, dx1 = aa.y - mu, dx2 = aa.z - mu, dx3 = aa.w - mu;
    float dx4 = ab.x - mu, dx5 = ab.y - mu, dx6 = ab.z - mu, dx7 = ab.w - mu;
    float s2v = dx0 * dx0 + dx1 * dx1 + dx2 * dx2 + dx3 * dx3
              + dx4 * dx4 + dx5 * dx5 + dx6 * dx6 + dx7 * dx7;
    s2v += __shfl_xor(s2v, 1);
    s2v += __shfl_xor(s2v, 2);
    s2v += __shfl_xor(s2v, 4);
    float var = s2v * (1.0f / DD);
    float is = rsqrtf(var + 1e-5f);
    float4 g4a = *(const float4*)(g + qi * 8);
    float4 g4b = *(const float4*)(g + qi * 8 + 4);
    float4 b4a = *(const float4*)(b + qi * 8);
    float4 b4b = *(const float4*)(b + qi * 8 + 4);
    float4 ya, yb;
    ya.x = fmaxf(dx0 * is * g4a.x + b4a.x, 0.0f);
    ya.y = fmaxf(dx1 * is * g4a.y + b4a.y, 0.0f);
    ya.z = fmaxf(dx2 * is * g4a.z + b4a.z, 0.0f);
    ya.w = fmaxf(dx3 * is * g4a.w + b4a.w, 0.0f);
    yb.x = fmaxf(dx4 * is * g4b.x + b4b.x, 0.0f);
    yb.y = fmaxf(dx5 * is * g4b.y + b4b.y, 0.0f);
    yb.z = fmaxf(dx6 * is * g4b.z + b4b.z, 0.0f);
    yb.w = fmaxf(dx7 * is * g4b.w + b4b.w, 0.0f);
    if (grp == 0) {
        if (out) {
            *(float4*)(out + ro) = ya;
            *(float4*)(out + ro + 4) = yb;
        }
        uint4 hv;
        hv.x = pk2u(ya.x, ya.y);
        hv.y = pk2u(ya.z, ya.w);
        hv.z = pk2u(yb.x, yb.y);
        hv.w = pk2u(yb.z, yb.w);
        *(uint4*)(hbf_out + ro) = hv;
    }
}

extern "C" void kernel_launch(void* const* d_in, const int* in_sizes, int n_in,
                              void* d_out, int out_size, void* d_ws, size_t ws_size,
                              hipStream_t stream) {
    const int D = DD;
    const float* x = (const float*)d_in[0];
    const int n = in_sizes[0] / D;       // 50000
    const int* ei = (const int*)d_in[1];
    const int E = in_sizes[1] / 2;       // 1e6
    const int* srcp = ei;
    const int* dstp = ei + E;
    const int nbw = (n + 1) / 2;         // bin-pair words (25000)

    static bool s_attr = false;
    if (!s_attr) {
        s_attr = true;
        (void)hipFuncSetAttribute((const void*)hist_prep,
                                  hipFuncAttributeMaxDynamicSharedMemorySize, 102400);
        (void)hipFuncSetAttribute((const void*)scatter2,
                                  hipFuncAttributeMaxDynamicSharedMemorySize, 102400);
    }

    char* wsp = (char*)d_ws;
    auto take = [&](size_t bytes) {
        char* p = wsp;
        wsp += (bytes + 255) & ~(size_t)255;
        return (void*)p;
    };
    int* counts    = (int*)take((size_t)n * 4);
    int* row_ptr   = (int*)take((size_t)(n + 1) * 4);
    unsigned* cb   = (unsigned*)take((size_t)NB_HIST * nbw * 4);   // 12.8 MB
    int* col       = (int*)take((size_t)E * 4);
    int* localscan = (int*)take((size_t)n * 4);
    int* blockSums = (int*)take((size_t)1024 * 4);
    size_t fsz = (size_t)n * D * 4;
    unsigned short* qb  = (unsigned short*)take(fsz / 2);   // f16 q (pre-scaled)
    unsigned char* kvb  = (unsigned char*)take(fsz / 2);    // fp8 k|v rows: n*128B
    unsigned short* sb  = (unsigned short*)take(fsz / 2);   // f16 skip+residual
    unsigned short* hbf = (unsigned short*)take(fsz / 2);   // f16 h (layer carrier)
    unsigned short* Wt  = (unsigned short*)take((size_t)16 * 4096 * 2);

    // ---- CSR build + prep (no global atomics) ----
    int tb = 256;
    size_t ldsH = (size_t)nbw * 4;       // 100 KB
    int nbScan = (n + 1023) / 1024;
    hist_prep<<<NB_HIST, 1024, ldsH, stream>>>(
        dstp, cb, E, nbw,
        x, hbf, n * D,
        (const float*)d_in[2], (const float*)d_in[4], (const float*)d_in[6],
        (const float*)d_in[8], (const float*)d_in[12], (const float*)d_in[14],
        (const float*)d_in[16], (const float*)d_in[18], Wt);
    prefix_blk<<<(nbw + tb - 1) / tb, tb, 0, stream>>>(cb, counts, nbw, n);
    scan_local<<<nbScan, 1024, 0, stream>>>(counts, localscan, blockSums, n);
    scan_tops<<<1, 64, 0, stream>>>(blockSums, nbScan);
    emit_rowptr<<<(n + tb - 1) / tb, tb, 0, stream>>>(localscan, blockSums, row_ptr, n, E);
    scatter2<<<NB_HIST, 1024, ldsH, stream>>>(srcp, dstp, cb, row_ptr, col, E, nbw);

    // ---- 4 conv layers ----
    int ntiles = n / 16;                 // 3125
    int nba = (n + 3) / 4;
    for (int layer = 0; layer < 4; ++layer) {
        const float *bq_, *bk_, *bv_, *bs_, *g_, *b_;
        if (layer == 0) {
            bq_ = (const float*)d_in[3];  bk_ = (const float*)d_in[5];
            bv_ = (const float*)d_in[7];  bs_ = (const float*)d_in[9];
            g_  = (const float*)d_in[10]; b_  = (const float*)d_in[11];
        } else {
            int i = layer - 1;
            bq_ = (const float*)d_in[13] + (size_t)i * D;
            bk_ = (const float*)d_in[15] + (size_t)i * D;
            bv_ = (const float*)d_in[17] + (size_t)i * D;
            bs_ = (const float*)d_in[19] + (size_t)i * D;
            g_  = (const float*)d_in[20] + (size_t)i * D;
            b_  = (const float*)d_in[21] + (size_t)i * D;
        }
        gemm_mfma<<<512, 256, 0, stream>>>(hbf, Wt + (size_t)layer * 4 * 4096,
                                           bq_, bk_, bv_, bs_,
                                           layer == 0 ? 0 : 1,
                                           qb, kvb, sb, ntiles);
        attn_agg_ln<<<nba, 256, 0, stream>>>(qb, kvb, sb, row_ptr, col, g_, b_,
                                             layer == 3 ? (float*)d_out : nullptr,
                                             hbf, n);
    }
}

// Round 20
// 346.020 us; speedup vs baseline: 1.0405x; 1.0241x over previous
//
#include <hip/hip_runtime.h>
#include <math.h>

// UniMP / TransformerConv x4 (heads=1), N=50000, E=1e6, D=64.
// R24: overlap scatter with layer-0 gemm. R23 counters: scatter2 = 47us on
//      128 blocks -- HALF the 256-CU chip idle (100KB LDS -> 1 blk/CU, only
//      128 blocks exist). scatter2 (reads row_ptr/cb/dst/src, writes col)
//      and layer-0 gemm (reads hbf/Wt, writes q/kv/sb) share NO data; fuse:
//      one 256-block/1024-thread kernel, blocks 0-127 = scatter2 verbatim,
//      blocks 128-255 = 4 virtual gemm blocks each (wave role=(tid>>6)&3,
//      vbid=(blk-128)*4+(tid>>8), tile stride 512 -- same mapping as the
//      512x256 launch). attn0 launches after -> col complete. Serial 47+33
//      becomes ~max(47, gemm-on-half-GPU) ~= 50.
//      Everything else = R23/R20 best (353-354us, absmax 0.1171875).

#define DD 64
#define NB_HIST 128

typedef __attribute__((ext_vector_type(8))) _Float16 h8;   // 8 f16 (4 VGPR)
typedef __attribute__((ext_vector_type(2))) _Float16 h2;
typedef __attribute__((ext_vector_type(4))) float f32x4;
typedef __attribute__((ext_vector_type(2))) float f32x2;

#define QSCALE 0.18033688f   // (1/8) * log2(e): folded into Wq,bq at prep

__device__ __forceinline__ unsigned short f2h(float f) {
    union { _Float16 h; unsigned short u; } c;
    c.h = (_Float16)f;
    return c.u;
}
__device__ __forceinline__ h2 u2h2(unsigned u) {
    union { unsigned u; h2 h; } c; c.u = u; return c.h;
}
__device__ __forceinline__ unsigned pk2u(float a, float b) {  // v_cvt_pkrtz_f16_f32
    union { decltype(__builtin_amdgcn_cvt_pkrtz(0.f, 0.f)) h; unsigned u; } c;
    c.h = __builtin_amdgcn_cvt_pkrtz(a, b);
    return c.u;
}

// ---------------- CSR build + prep (fused) ----------------
__global__ __launch_bounds__(1024) void hist_prep(
    const int* __restrict__ dst, unsigned* __restrict__ cb, int E, int nbw,
    const float* __restrict__ x, unsigned short* __restrict__ hbf, int nD,
    const float* __restrict__ W0, const float* __restrict__ W1,
    const float* __restrict__ W2, const float* __restrict__ W3,
    const float* __restrict__ Wqs, const float* __restrict__ Wks,
    const float* __restrict__ Wvs, const float* __restrict__ Wss,
    unsigned short* __restrict__ Wt) {
    extern __shared__ unsigned hist[];          // nbw words
    int blk = blockIdx.x;
    for (int w = threadIdx.x; w < nbw; w += blockDim.x) hist[w] = 0;
    __syncthreads();
    int chunk = (E + gridDim.x - 1) / gridDim.x;
    int beg = blk * chunk;
    int end = min(E, beg + chunk);
    for (int e = beg + (int)threadIdx.x; e < end; e += blockDim.x) {
        int d = dst[e];
        atomicAdd(&hist[d >> 1], (d & 1) ? 0x10000u : 1u);
    }
    __syncthreads();
    unsigned* out = cb + (size_t)blk * nbw;
    for (int w = threadIdx.x; w < nbw; w += blockDim.x) out[w] = hist[w];

    // ---- prep tail (grid-stride over x-convert + weight transposes) ----
    int total = nD + 16 * 4096;
    int stride = gridDim.x * blockDim.x;
    for (int i = blk * blockDim.x + threadIdx.x; i < total; i += stride) {
        if (i < nD) { hbf[i] = f2h(x[i]); continue; }
        int id = i - nD;
        int mat = id >> 12, rem = id & 4095;
        int nn = rem >> 6, kk = rem & 63;
        int layer = mat >> 2, wh = mat & 3;
        const float* W;
        if (layer == 0) W = wh == 0 ? W0 : wh == 1 ? W1 : wh == 2 ? W2 : W3;
        else {
            const float* base = wh == 0 ? Wqs : wh == 1 ? Wks : wh == 2 ? Wvs : Wss;
            W = base + (size_t)(layer - 1) * 4096;
        }
        float val = W[kk * 64 + nn];
        if (wh == 0) val *= QSCALE;       // fold 1/sqrt(64)*log2(e) into Wq
        Wt[id] = f2h(val);                // Wt[mat][n][k]
    }
}

// 16-wide register batches; NB_HIST=128 -> 8 serial rounds.
__global__ __launch_bounds__(256) void prefix_blk(unsigned* __restrict__ cb,
                                                  int* __restrict__ counts,
                                                  int nbw, int n) {
    int w = blockIdx.x * blockDim.x + threadIdx.x;
    if (w >= nbw) return;
    unsigned acc = 0;
#pragma unroll 1
    for (int c = 0; c < NB_HIST; c += 16) {
        unsigned t[16];
#pragma unroll
        for (int j = 0; j < 16; ++j) t[j] = cb[(size_t)(c + j) * nbw + w];
#pragma unroll
        for (int j = 0; j < 16; ++j) {
            unsigned v = t[j];
            cb[(size_t)(c + j) * nbw + w] = acc;   // exclusive prefix (packed)
            acc += v;                              // halves independent (<65536)
        }
    }
    counts[2 * w] = (int)(acc & 0xffffu);
    int b1 = 2 * w + 1;
    if (b1 < n) counts[b1] = (int)(acc >> 16);
}

__global__ __launch_bounds__(1024) void scan_local(const int* __restrict__ counts,
                                                   int* __restrict__ localscan,
                                                   int* __restrict__ blockSums, int n) {
    __shared__ int sh[1024];
    int i = blockIdx.x * 1024 + threadIdx.x;
    int val = (i < n) ? counts[i] : 0;
    sh[threadIdx.x] = val;
    __syncthreads();
    for (int off = 1; off < 1024; off <<= 1) {
        int t = (threadIdx.x >= off) ? sh[threadIdx.x - off] : 0;
        __syncthreads();
        sh[threadIdx.x] += t;
        __syncthreads();
    }
    if (i < n) localscan[i] = sh[threadIdx.x] - val;
    if (threadIdx.x == 1023) blockSums[blockIdx.x] = sh[1023];
}

// single-WAVE exclusive scan of block sums (nb <= 64; n=50000 -> 49)
__global__ __launch_bounds__(64) void scan_tops(int* __restrict__ blockSums, int nb) {
    int i = threadIdx.x;
    int val = (i < nb) ? blockSums[i] : 0;
    int s = val;
#pragma unroll
    for (int off = 1; off < 64; off <<= 1) {
        int t = __shfl_up(s, off, 64);
        if (i >= off) s += t;
    }
    if (i < nb) blockSums[i] = s - val;   // exclusive
}

__global__ void emit_rowptr(const int* __restrict__ localscan,
                            const int* __restrict__ blockSums,
                            int* __restrict__ row_ptr, int n, int E) {
    int i = blockIdx.x * blockDim.x + threadIdx.x;
    if (i < n) row_ptr[i] = localscan[i] + blockSums[i >> 10];
    if (i == 0) row_ptr[n] = E;
}

// ---------------- shared gemm body ----------------
// One virtual block = 4 waves -> Q,K,V,S roles. A = W (frags resident), B = h.
// wave0: f16 q (QSCALE). wave1/2: fp8 into byte-interleaved 128B kv row.
// wave3: skip + residual (from f16 hbf), stored f16 into sb.
__device__ __forceinline__ void gemm_phase(
    const unsigned short* __restrict__ hbf, const unsigned short* __restrict__ Wt,
    const float* __restrict__ Bq, const float* __restrict__ Bk,
    const float* __restrict__ Bv, const float* __restrict__ Bs,
    int with_res,
    unsigned short* __restrict__ qO, unsigned char* __restrict__ kvO,
    unsigned short* __restrict__ sO, int ntiles,
    int vbid, int gstride, int lane, int wave) {
    int ml = lane & 15, ql = lane >> 4;

    const unsigned short* W = Wt + wave * 4096;
    h8 wfrag[4][2];     // A-frag: A[m=ml][k=ql*8+j] = Wt[t*16+ml][kh*32+ql*8+j]
#pragma unroll
    for (int t = 0; t < 4; ++t)
#pragma unroll
        for (int kh = 0; kh < 2; ++kh)
            wfrag[t][kh] = *(const h8*)(W + (t * 16 + ml) * 64 + kh * 32 + ql * 8);

    const float* bias = wave == 0 ? Bq : wave == 1 ? Bk : wave == 2 ? Bv : Bs;
    float4 bias4[4];
#pragma unroll
    for (int t = 0; t < 4; ++t) {
        bias4[t] = *(const float4*)(bias + t * 16 + ql * 4);
        if (wave == 0) {
            bias4[t].x *= QSCALE; bias4[t].y *= QSCALE;
            bias4[t].z *= QSCALE; bias4[t].w *= QSCALE;
        }
    }

    for (int tile = vbid; tile < ntiles; tile += gstride) {
        int node0 = tile * 16;           // n = 50000 = 3125 * 16, no partial tile
        h8 hfrag[2];                     // B-frag: B[k=ql*8+j][n=ml]
#pragma unroll
        for (int kh = 0; kh < 2; ++kh)
            hfrag[kh] = *(const h8*)(hbf + (size_t)(node0 + ml) * 64 + kh * 32 + ql * 8);
        f32x4 acc[4];
#pragma unroll
        for (int t = 0; t < 4; ++t) {
            acc[t][0] = bias4[t].x; acc[t][1] = bias4[t].y;
            acc[t][2] = bias4[t].z; acc[t][3] = bias4[t].w;
        }
#pragma unroll
        for (int t = 0; t < 4; ++t)
#pragma unroll
            for (int kh = 0; kh < 2; ++kh)
                acc[t] = __builtin_amdgcn_mfma_f32_16x16x32_f16(
                    wfrag[t][kh], hfrag[kh], acc[t], 0, 0, 0);

        size_t rowe = (size_t)(node0 + ml) * 64;
        if (wave == 0) {
#pragma unroll
            for (int t = 0; t < 4; ++t) {
                uint2 st;
                st.x = pk2u(acc[t][0], acc[t][1]);
                st.y = pk2u(acc[t][2], acc[t][3]);
                *(uint2*)(qO + rowe + t * 16 + ql * 4) = st;
            }
        } else if (wave == 3) {
#pragma unroll
            for (int t = 0; t < 4; ++t) {
                float4 st = {acc[t][0], acc[t][1], acc[t][2], acc[t][3]};
                if (with_res) {
                    uint2 hv = *(const uint2*)(hbf + rowe + t * 16 + ql * 4);
                    h2 r0 = u2h2(hv.x), r1 = u2h2(hv.y);
                    st.x += (float)r0[0]; st.y += (float)r0[1];
                    st.z += (float)r1[0]; st.w += (float)r1[1];
                }
                uint2 sp;
                sp.x = pk2u(st.x, st.y);
                sp.y = pk2u(st.z, st.w);
                *(uint2*)(sO + rowe + t * 16 + ql * 4) = sp;
            }
        } else {
            // dims [t*16+ql*4, +4) -> chunk = t*2 + (ql>>1), byte (ql&1)*4
            size_t kvr = (size_t)(node0 + ml) * 128 + (wave == 2 ? 8 : 0);
#pragma unroll
            for (int t = 0; t < 4; ++t) {
                int pk = __builtin_amdgcn_cvt_pk_fp8_f32(acc[t][0], acc[t][1], 0, false);
                pk = __builtin_amdgcn_cvt_pk_fp8_f32(acc[t][2], acc[t][3], pk, true);
                size_t addr = kvr + (size_t)(t * 2 + (ql >> 1)) * 16 + (ql & 1) * 4;
                *(unsigned*)(kvO + addr) = (unsigned)pk;
            }
        }
    }
}

// gemm for layers 1-3 (512 blocks x 256 threads, as measured-best)
__global__ __launch_bounds__(256) void gemm_mfma(
    const unsigned short* __restrict__ hbf, const unsigned short* __restrict__ Wt,
    const float* __restrict__ Bq, const float* __restrict__ Bk,
    const float* __restrict__ Bv, const float* __restrict__ Bs,
    int with_res,
    unsigned short* __restrict__ qO, unsigned char* __restrict__ kvO,
    unsigned short* __restrict__ sO, int ntiles) {
    gemm_phase(hbf, Wt, Bq, Bk, Bv, Bs, with_res, qO, kvO, sO, ntiles,
               blockIdx.x, gridDim.x, threadIdx.x & 63, threadIdx.x >> 6);
}

// ---- fused: blocks 0-127 scatter (col build), 128-255 layer-0 gemm ----
// Independent data -> concurrent use of all 256 CUs instead of half idle.
__global__ __launch_bounds__(1024) void scatter_gemm(
    const int* __restrict__ src, const int* __restrict__ dst,
    const unsigned* __restrict__ cb, const int* __restrict__ row_ptr,
    int* __restrict__ col, int E, int nbw,
    const unsigned short* __restrict__ hbf, const unsigned short* __restrict__ Wt,
    const float* __restrict__ Bq, const float* __restrict__ Bk,
    const float* __restrict__ Bv, const float* __restrict__ Bs,
    unsigned short* __restrict__ qO, unsigned char* __restrict__ kvO,
    unsigned short* __restrict__ sO, int ntiles) {
    if (blockIdx.x < NB_HIST) {
        // ---- scatter2 body (verbatim; chunk over NB_HIST blocks) ----
        extern __shared__ unsigned hist[];
        int blk = blockIdx.x;
        for (int w = threadIdx.x; w < nbw; w += blockDim.x) hist[w] = 0;
        __syncthreads();
        const unsigned* pref = cb + (size_t)blk * nbw;
        int chunk = (E + NB_HIST - 1) / NB_HIST;
        int beg = blk * chunk;
        int end = min(E, beg + chunk);
        for (int e = beg + (int)threadIdx.x; e < end; e += blockDim.x) {
            int d = dst[e];
            unsigned sh = (unsigned)(d & 1) * 16u;
            unsigned old = atomicAdd(&hist[d >> 1], 1u << sh);
            unsigned lr = (old >> sh) & 0xffffu;
            unsigned pre = (pref[d >> 1] >> sh) & 0xffffu;
            int slot = row_ptr[d] + (int)pre + (int)lr;
            __builtin_nontemporal_store(src[e] << 7, &col[slot]);
        }
    } else {
        // ---- layer-0 gemm: 4 virtual 4-wave blocks per 1024-thread block ----
        int vbid = (blockIdx.x - NB_HIST) * 4 + ((int)threadIdx.x >> 8);
        int lane = threadIdx.x & 63;
        int wave = ((int)threadIdx.x >> 6) & 3;
        gemm_phase(hbf, Wt, Bq, Bk, Bv, Bs, 0 /*layer0: no residual*/,
                   qO, kvO, sO, ntiles, vbid, (256 - NB_HIST) * 4, lane, wave);
    }
}

// ---------------- fused attention + LN ----------------
// One wave per dst node; 8 groups of 8 lanes; x2 volley (16 edge-slots).
// Byte-interleaved fp8 kv row: lane qi reads ONE uint4 (k-chunk | v-chunk).
// Logits carry log2(e) pre-scale -> p = exp2f(d). fp32 accum, LN+ReLU.
#define EDGE_COMP(U) do {                                                      \
    f32x2 k0 = __builtin_amdgcn_cvt_pk_f32_fp8((U).x, false);                  \
    f32x2 k1 = __builtin_amdgcn_cvt_pk_f32_fp8((U).x, true);                   \
    f32x2 k2 = __builtin_amdgcn_cvt_pk_f32_fp8((U).y, false);                  \
    f32x2 k3 = __builtin_amdgcn_cvt_pk_f32_fp8((U).y, true);                   \
    float d = qf0 * k0[0];                                                     \
    d = fmaf(qf1, k0[1], d); d = fmaf(qf2, k1[0], d); d = fmaf(qf3, k1[1], d); \
    d = fmaf(qf4, k2[0], d); d = fmaf(qf5, k2[1], d); d = fmaf(qf6, k3[0], d); \
    d = fmaf(qf7, k3[1], d);                                                   \
    d += __shfl_xor(d, 1); d += __shfl_xor(d, 2); d += __shfl_xor(d, 4);       \
    float p = exp2f(d); ssum += p;                                             \
    f32x2 w0 = __builtin_amdgcn_cvt_pk_f32_fp8((U).z, false);                  \
    f32x2 w1 = __builtin_amdgcn_cvt_pk_f32_fp8((U).z, true);                   \
    f32x2 w2 = __builtin_amdgcn_cvt_pk_f32_fp8((U).w, false);                  \
    f32x2 w3 = __builtin_amdgcn_cvt_pk_f32_fp8((U).w, true);                   \
    aa.x = fmaf(w0[0], p, aa.x); aa.y = fmaf(w0[1], p, aa.y);                  \
    aa.z = fmaf(w1[0], p, aa.z); aa.w = fmaf(w1[1], p, aa.w);                  \
    ab.x = fmaf(w2[0], p, ab.x); ab.y = fmaf(w2[1], p, ab.y);                  \
    ab.z = fmaf(w3[0], p, ab.z); ab.w = fmaf(w3[1], p, ab.w);                  \
} while (0)

__global__ __launch_bounds__(256) void attn_agg_ln(
    const unsigned short* __restrict__ qh, const unsigned char* __restrict__ kv,
    const unsigned short* __restrict__ sk,
    const int* __restrict__ row_ptr, const int* __restrict__ col,
    const float* __restrict__ g, const float* __restrict__ b,
    float* __restrict__ out, unsigned short* __restrict__ hbf_out, int n) {
    int node = blockIdx.x * 4 + (threadIdx.x >> 6);
    int lane = threadIdx.x & 63;
    if (node >= n) return;
    int grp = lane >> 3;
    int qi = lane & 7;

    size_t ro = (size_t)node * DD + qi * 8;
    uint4 qu = *(const uint4*)(qh + ro);          // 8 f16, pre-scaled QSCALE
    uint4 su = *(const uint4*)(sk + ro);          // 8 f16 skip(+residual)
    int beg = row_ptr[node], end = row_ptr[node + 1];

    // unpack q to 8 f32 once (feeds fp8-k fma chain)
    h2 q0 = u2h2(qu.x), q1 = u2h2(qu.y), q2 = u2h2(qu.z), q3 = u2h2(qu.w);
    float qf0 = (float)q0[0], qf1 = (float)q0[1], qf2 = (float)q1[0], qf3 = (float)q1[1];
    float qf4 = (float)q2[0], qf5 = (float)q2[1], qf6 = (float)q3[0], qf7 = (float)q3[1];

    float ssum = 0.0f;
    float4 aa = {0.f, 0.f, 0.f, 0.f}, ab = {0.f, 0.f, 0.f, 0.f};

    int e = beg + grp;
    int cv0 = (e < end) ? col[e] : -1;
    int cv1 = (e + 8 < end) ? col[e + 8] : -1;
    for (int e0 = beg; e0 < end; e0 += 16) {
        bool a0 = cv0 >= 0, a1 = cv1 >= 0;
        uint4 u0, u1;
        if (a0) u0 = *(const uint4*)(kv + cv0 + qi * 16);   // k|v chunk, one load
        if (a1) u1 = *(const uint4*)(kv + cv1 + qi * 16);
        e += 16;
        cv0 = (e < end) ? col[e] : -1;
        cv1 = (e + 8 < end) ? col[e + 8] : -1;
        if (a0) EDGE_COMP(u0);
        if (a1) EDGE_COMP(u1);
    }

#pragma unroll
    for (int off = 8; off <= 32; off <<= 1) {
        ssum += __shfl_xor(ssum, off);
        aa.x += __shfl_xor(aa.x, off); aa.y += __shfl_xor(aa.y, off);
        aa.z += __shfl_xor(aa.z, off); aa.w += __shfl_xor(aa.w, off);
        ab.x += __shfl_xor(ab.x, off); ab.y += __shfl_xor(ab.y, off);
        ab.z += __shfl_xor(ab.z, off); ab.w += __shfl_xor(ab.w, off);
    }
    float inv = (end > beg) ? 1.0f / ssum : 0.0f;
    aa.x *= inv; aa.y *= inv; aa.z *= inv; aa.w *= inv;
    ab.x *= inv; ab.y *= inv; ab.z *= inv; ab.w *= inv;

    {   // + skip (+ residual), f16 -> f32
        h2 t0 = u2h2(su.x), t1 = u2h2(su.y), t2 = u2h2(su.z), t3 = u2h2(su.w);
        aa.x += (float)t0[0]; aa.y += (float)t0[1];
        aa.z += (float)t1[0]; aa.w += (float)t1[1];
        ab.x += (float)t2[0]; ab.y += (float)t2[1];
        ab.z += (float)t3[0]; ab.w += (float)t3[1];
    }

    float s1 = aa.x + aa.y + aa.z + aa.w + ab.x + ab.y + ab.z + ab.w;
    s1 += __shfl_xor(s1, 1);
    s1 += __shfl_xor(s1, 2);
    s1 += __shfl_xor(s1, 4);
    float mu = s1 * (1.0f / DD);
    float dx0 = aa.x - mu, dx1 = aa.y - mu, dx2 = aa.z - mu, dx3 = aa.w - mu;
    float dx4 = ab.x - mu, dx5 = ab.y - mu, dx6 = ab.z - mu, dx7 = ab.w - mu;
    float s2v = dx0 * dx0 + dx1 * dx1 + dx2 * dx2 + dx3 * dx3
              + dx4 * dx4 + dx5 * dx5 + dx6 * dx6 + dx7 * dx7;
    s2v += __shfl_xor(s2v, 1);
    s2v += __shfl_xor(s2v, 2);
    s2v += __shfl_xor(s2v, 4);
    float var = s2v * (1.0f / DD);
    float is = rsqrtf(var + 1e-5f);
    float4 g4a = *(const float4*)(g + qi * 8);
    float4 g4b = *(const float4*)(g + qi * 8 + 4);
    float4 b4a = *(const float4*)(b + qi * 8);
    float4 b4b = *(const float4*)(b + qi * 8 + 4);
    float4 ya, yb;
    ya.x = fmaxf(dx0 * is * g4a.x + b4a.x, 0.0f);
    ya.y = fmaxf(dx1 * is * g4a.y + b4a.y, 0.0f);
    ya.z = fmaxf(dx2 * is * g4a.z + b4a.z, 0.0f);
    ya.w = fmaxf(dx3 * is * g4a.w + b4a.w, 0.0f);
    yb.x = fmaxf(dx4 * is * g4b.x + b4b.x, 0.0f);
    yb.y = fmaxf(dx5 * is * g4b.y + b4b.y, 0.0f);
    yb.z = fmaxf(dx6 * is * g4b.z + b4b.z, 0.0f);
    yb.w = fmaxf(dx7 * is * g4b.w + b4b.w, 0.0f);
    if (grp == 0) {
        if (out) {
            *(float4*)(out + ro) = ya;
            *(float4*)(out + ro + 4) = yb;
        }
        uint4 hv;
        hv.x = pk2u(ya.x, ya.y);
        hv.y = pk2u(ya.z, ya.w);
        hv.z = pk2u(yb.x, yb.y);
        hv.w = pk2u(yb.z, yb.w);
        *(uint4*)(hbf_out + ro) = hv;
    }
}

extern "C" void kernel_launch(void* const* d_in, const int* in_sizes, int n_in,
                              void* d_out, int out_size, void* d_ws, size_t ws_size,
                              hipStream_t stream) {
    const int D = DD;
    const float* x = (const float*)d_in[0];
    const int n = in_sizes[0] / D;       // 50000
    const int* ei = (const int*)d_in[1];
    const int E = in_sizes[1] / 2;       // 1e6
    const int* srcp = ei;
    const int* dstp = ei + E;
    const int nbw = (n + 1) / 2;         // bin-pair words (25000)

    static bool s_attr = false;
    if (!s_attr) {
        s_attr = true;
        (void)hipFuncSetAttribute((const void*)hist_prep,
                                  hipFuncAttributeMaxDynamicSharedMemorySize, 102400);
        (void)hipFuncSetAttribute((const void*)scatter_gemm,
                                  hipFuncAttributeMaxDynamicSharedMemorySize, 102400);
    }

    char* wsp = (char*)d_ws;
    auto take = [&](size_t bytes) {
        char* p = wsp;
        wsp += (bytes + 255) & ~(size_t)255;
        return (void*)p;
    };
    int* counts    = (int*)take((size_t)n * 4);
    int* row_ptr   = (int*)take((size_t)(n + 1) * 4);
    unsigned* cb   = (unsigned*)take((size_t)NB_HIST * nbw * 4);   // 12.8 MB
    int* col       = (int*)take((size_t)E * 4);
    int* localscan = (int*)take((size_t)n * 4);
    int* blockSums = (int*)take((size_t)1024 * 4);
    size_t fsz = (size_t)n * D * 4;
    unsigned short* qb  = (unsigned short*)take(fsz / 2);   // f16 q (pre-scaled)
    unsigned char* kvb  = (unsigned char*)take(fsz / 2);    // fp8 k|v rows: n*128B
    unsigned short* sb  = (unsigned short*)take(fsz / 2);   // f16 skip+residual
    unsigned short* hbf = (unsigned short*)take(fsz / 2);   // f16 h (layer carrier)
    unsigned short* Wt  = (unsigned short*)take((size_t)16 * 4096 * 2);

    // ---- CSR build + prep (no global atomics) ----
    int tb = 256;
    size_t ldsH = (size_t)nbw * 4;       // 100 KB
    int nbScan = (n + 1023) / 1024;
    hist_prep<<<NB_HIST, 1024, ldsH, stream>>>(
        dstp, cb, E, nbw,
        x, hbf, n * D,
        (const float*)d_in[2], (const float*)d_in[4], (const float*)d_in[6],
        (const float*)d_in[8], (const float*)d_in[12], (const float*)d_in[14],
        (const float*)d_in[16], (const float*)d_in[18], Wt);
    prefix_blk<<<(nbw + tb - 1) / tb, tb, 0, stream>>>(cb, counts, nbw, n);
    scan_local<<<nbScan, 1024, 0, stream>>>(counts, localscan, blockSums, n);
    scan_tops<<<1, 64, 0, stream>>>(blockSums, nbScan);
    emit_rowptr<<<(n + tb - 1) / tb, tb, 0, stream>>>(localscan, blockSums, row_ptr, n, E);

    // ---- fused scatter + layer-0 gemm (independent; 256 CUs busy) ----
    int ntiles = n / 16;                 // 3125
    int nba = (n + 3) / 4;
    scatter_gemm<<<NB_HIST * 2, 1024, ldsH, stream>>>(
        srcp, dstp, cb, row_ptr, col, E, nbw,
        hbf, Wt,
        (const float*)d_in[3], (const float*)d_in[5],
        (const float*)d_in[7], (const float*)d_in[9],
        qb, kvb, sb, ntiles);
    attn_agg_ln<<<nba, 256, 0, stream>>>(qb, kvb, sb, row_ptr, col,
                                         (const float*)d_in[10],
                                         (const float*)d_in[11],
                                         nullptr, hbf, n);

    // ---- layers 1-3 ----
    for (int layer = 1; layer < 4; ++layer) {
        int i = layer - 1;
        const float* bq_ = (const float*)d_in[13] + (size_t)i * D;
        const float* bk_ = (const float*)d_in[15] + (size_t)i * D;
        const float* bv_ = (const float*)d_in[17] + (size_t)i * D;
        const float* bs_ = (const float*)d_in[19] + (size_t)i * D;
        const float* g_  = (const float*)d_in[20] + (size_t)i * D;
        const float* b_  = (const float*)d_in[21] + (size_t)i * D;
        gemm_mfma<<<512, 256, 0, stream>>>(hbf, Wt + (size_t)layer * 4 * 4096,
                                           bq_, bk_, bv_, bs_, 1,
                                           qb, kvb, sb, ntiles);
        attn_agg_ln<<<nba, 256, 0, stream>>>(qb, kvb, sb, row_ptr, col, g_, b_,
                                             layer == 3 ? (float*)d_out : nullptr,
                                             hbf, n);
    }
}

// Round 21
// 343.636 us; speedup vs baseline: 1.0477x; 1.0069x over previous
//
#include <hip/hip_runtime.h>
#include <math.h>

// UniMP / TransformerConv x4 (heads=1), N=50000, E=1e6, D=64.
// R25: R24 (346.0us best: scatter overlapped with layer-0 gemm) + two safe
//      consolidations: (1) scan_tops merged into emit_rowptr (each block
//      redundantly wave-scans the 49 block sums -- removes one full-GPU
//      boundary without serializing parallel work); (2) attn layer 3 skips
//      the dead hbf store (-6.4MB write).
//      Settled by R21/R22/R24: scatter's ~47us is a global random-line
//      ownership limit -- can only be hidden, and gemm-0 (the only col-
//      independent work) is already inside scatter_gemm.
//      Stack: f16 MFMA gemm, fp8-e4m3 K/V byte-interleaved 128B rows,
//      f16 q (QSCALE) + exp2 softmax, f16 sb/hbf, LDS-histogram CSR.

#define DD 64
#define NB_HIST 128

typedef __attribute__((ext_vector_type(8))) _Float16 h8;   // 8 f16 (4 VGPR)
typedef __attribute__((ext_vector_type(2))) _Float16 h2;
typedef __attribute__((ext_vector_type(4))) float f32x4;
typedef __attribute__((ext_vector_type(2))) float f32x2;

#define QSCALE 0.18033688f   // (1/8) * log2(e): folded into Wq,bq at prep

__device__ __forceinline__ unsigned short f2h(float f) {
    union { _Float16 h; unsigned short u; } c;
    c.h = (_Float16)f;
    return c.u;
}
__device__ __forceinline__ h2 u2h2(unsigned u) {
    union { unsigned u; h2 h; } c; c.u = u; return c.h;
}
__device__ __forceinline__ unsigned pk2u(float a, float b) {  // v_cvt_pkrtz_f16_f32
    union { decltype(__builtin_amdgcn_cvt_pkrtz(0.f, 0.f)) h; unsigned u; } c;
    c.h = __builtin_amdgcn_cvt_pkrtz(a, b);
    return c.u;
}

// ---------------- CSR build + prep (fused) ----------------
__global__ __launch_bounds__(1024) void hist_prep(
    const int* __restrict__ dst, unsigned* __restrict__ cb, int E, int nbw,
    const float* __restrict__ x, unsigned short* __restrict__ hbf, int nD,
    const float* __restrict__ W0, const float* __restrict__ W1,
    const float* __restrict__ W2, const float* __restrict__ W3,
    const float* __restrict__ Wqs, const float* __restrict__ Wks,
    const float* __restrict__ Wvs, const float* __restrict__ Wss,
    unsigned short* __restrict__ Wt) {
    extern __shared__ unsigned hist[];          // nbw words
    int blk = blockIdx.x;
    for (int w = threadIdx.x; w < nbw; w += blockDim.x) hist[w] = 0;
    __syncthreads();
    int chunk = (E + gridDim.x - 1) / gridDim.x;
    int beg = blk * chunk;
    int end = min(E, beg + chunk);
    for (int e = beg + (int)threadIdx.x; e < end; e += blockDim.x) {
        int d = dst[e];
        atomicAdd(&hist[d >> 1], (d & 1) ? 0x10000u : 1u);
    }
    __syncthreads();
    unsigned* out = cb + (size_t)blk * nbw;
    for (int w = threadIdx.x; w < nbw; w += blockDim.x) out[w] = hist[w];

    // ---- prep tail (grid-stride over x-convert + weight transposes) ----
    int total = nD + 16 * 4096;
    int stride = gridDim.x * blockDim.x;
    for (int i = blk * blockDim.x + threadIdx.x; i < total; i += stride) {
        if (i < nD) { hbf[i] = f2h(x[i]); continue; }
        int id = i - nD;
        int mat = id >> 12, rem = id & 4095;
        int nn = rem >> 6, kk = rem & 63;
        int layer = mat >> 2, wh = mat & 3;
        const float* W;
        if (layer == 0) W = wh == 0 ? W0 : wh == 1 ? W1 : wh == 2 ? W2 : W3;
        else {
            const float* base = wh == 0 ? Wqs : wh == 1 ? Wks : wh == 2 ? Wvs : Wss;
            W = base + (size_t)(layer - 1) * 4096;
        }
        float val = W[kk * 64 + nn];
        if (wh == 0) val *= QSCALE;       // fold 1/sqrt(64)*log2(e) into Wq
        Wt[id] = f2h(val);                // Wt[mat][n][k]
    }
}

// 16-wide register batches; NB_HIST=128 -> 8 serial rounds.
__global__ __launch_bounds__(256) void prefix_blk(unsigned* __restrict__ cb,
                                                  int* __restrict__ counts,
                                                  int nbw, int n) {
    int w = blockIdx.x * blockDim.x + threadIdx.x;
    if (w >= nbw) return;
    unsigned acc = 0;
#pragma unroll 1
    for (int c = 0; c < NB_HIST; c += 16) {
        unsigned t[16];
#pragma unroll
        for (int j = 0; j < 16; ++j) t[j] = cb[(size_t)(c + j) * nbw + w];
#pragma unroll
        for (int j = 0; j < 16; ++j) {
            unsigned v = t[j];
            cb[(size_t)(c + j) * nbw + w] = acc;   // exclusive prefix (packed)
            acc += v;                              // halves independent (<65536)
        }
    }
    counts[2 * w] = (int)(acc & 0xffffu);
    int b1 = 2 * w + 1;
    if (b1 < n) counts[b1] = (int)(acc >> 16);
}

__global__ __launch_bounds__(1024) void scan_local(const int* __restrict__ counts,
                                                   int* __restrict__ localscan,
                                                   int* __restrict__ blockSums, int n) {
    __shared__ int sh[1024];
    int i = blockIdx.x * 1024 + threadIdx.x;
    int val = (i < n) ? counts[i] : 0;
    sh[threadIdx.x] = val;
    __syncthreads();
    for (int off = 1; off < 1024; off <<= 1) {
        int t = (threadIdx.x >= off) ? sh[threadIdx.x - off] : 0;
        __syncthreads();
        sh[threadIdx.x] += t;
        __syncthreads();
    }
    if (i < n) localscan[i] = sh[threadIdx.x] - val;
    if (threadIdx.x == 1023) blockSums[blockIdx.x] = sh[1023];
}

// emit_rowptr with INLINE tops-scan: wave 0 of each block redundantly
// exclusive-scans the nb (<=64) raw block sums; removes the scan_tops
// kernel + one full-GPU drain/refill boundary.
__global__ __launch_bounds__(256) void emit_rowptr(const int* __restrict__ localscan,
                                                   const int* __restrict__ blockSums,
                                                   int* __restrict__ row_ptr,
                                                   int n, int E, int nb) {
    __shared__ int ex[64];
    int tid = threadIdx.x;
    if (tid < 64) {                      // single wave: shfl exclusive scan
        int v = (tid < nb) ? blockSums[tid] : 0;
        int s = v;
#pragma unroll
        for (int off = 1; off < 64; off <<= 1) {
            int t = __shfl_up(s, off, 64);
            if (tid >= off) s += t;
        }
        ex[tid] = s - v;
    }
    __syncthreads();
    int i = blockIdx.x * 256 + tid;
    if (i < n) row_ptr[i] = localscan[i] + ex[i >> 10];
    if (i == 0) row_ptr[n] = E;
}

// ---------------- shared gemm body ----------------
// One virtual block = 4 waves -> Q,K,V,S roles. A = W (frags resident), B = h.
// wave0: f16 q (QSCALE). wave1/2: fp8 into byte-interleaved 128B kv row.
// wave3: skip + residual (from f16 hbf), stored f16 into sb.
__device__ __forceinline__ void gemm_phase(
    const unsigned short* __restrict__ hbf, const unsigned short* __restrict__ Wt,
    const float* __restrict__ Bq, const float* __restrict__ Bk,
    const float* __restrict__ Bv, const float* __restrict__ Bs,
    int with_res,
    unsigned short* __restrict__ qO, unsigned char* __restrict__ kvO,
    unsigned short* __restrict__ sO, int ntiles,
    int vbid, int gstride, int lane, int wave) {
    int ml = lane & 15, ql = lane >> 4;

    const unsigned short* W = Wt + wave * 4096;
    h8 wfrag[4][2];     // A-frag: A[m=ml][k=ql*8+j] = Wt[t*16+ml][kh*32+ql*8+j]
#pragma unroll
    for (int t = 0; t < 4; ++t)
#pragma unroll
        for (int kh = 0; kh < 2; ++kh)
            wfrag[t][kh] = *(const h8*)(W + (t * 16 + ml) * 64 + kh * 32 + ql * 8);

    const float* bias = wave == 0 ? Bq : wave == 1 ? Bk : wave == 2 ? Bv : Bs;
    float4 bias4[4];
#pragma unroll
    for (int t = 0; t < 4; ++t) {
        bias4[t] = *(const float4*)(bias + t * 16 + ql * 4);
        if (wave == 0) {
            bias4[t].x *= QSCALE; bias4[t].y *= QSCALE;
            bias4[t].z *= QSCALE; bias4[t].w *= QSCALE;
        }
    }

    for (int tile = vbid; tile < ntiles; tile += gstride) {
        int node0 = tile * 16;           // n = 50000 = 3125 * 16, no partial tile
        h8 hfrag[2];                     // B-frag: B[k=ql*8+j][n=ml]
#pragma unroll
        for (int kh = 0; kh < 2; ++kh)
            hfrag[kh] = *(const h8*)(hbf + (size_t)(node0 + ml) * 64 + kh * 32 + ql * 8);
        f32x4 acc[4];
#pragma unroll
        for (int t = 0; t < 4; ++t) {
            acc[t][0] = bias4[t].x; acc[t][1] = bias4[t].y;
            acc[t][2] = bias4[t].z; acc[t][3] = bias4[t].w;
        }
#pragma unroll
        for (int t = 0; t < 4; ++t)
#pragma unroll
            for (int kh = 0; kh < 2; ++kh)
                acc[t] = __builtin_amdgcn_mfma_f32_16x16x32_f16(
                    wfrag[t][kh], hfrag[kh], acc[t], 0, 0, 0);

        size_t rowe = (size_t)(node0 + ml) * 64;
        if (wave == 0) {
#pragma unroll
            for (int t = 0; t < 4; ++t) {
                uint2 st;
                st.x = pk2u(acc[t][0], acc[t][1]);
                st.y = pk2u(acc[t][2], acc[t][3]);
                *(uint2*)(qO + rowe + t * 16 + ql * 4) = st;
            }
        } else if (wave == 3) {
#pragma unroll
            for (int t = 0; t < 4; ++t) {
                float4 st = {acc[t][0], acc[t][1], acc[t][2], acc[t][3]};
                if (with_res) {
                    uint2 hv = *(const uint2*)(hbf + rowe + t * 16 + ql * 4);
                    h2 r0 = u2h2(hv.x), r1 = u2h2(hv.y);
                    st.x += (float)r0[0]; st.y += (float)r0[1];
                    st.z += (float)r1[0]; st.w += (float)r1[1];
                }
                uint2 sp;
                sp.x = pk2u(st.x, st.y);
                sp.y = pk2u(st.z, st.w);
                *(uint2*)(sO + rowe + t * 16 + ql * 4) = sp;
            }
        } else {
            // dims [t*16+ql*4, +4) -> chunk = t*2 + (ql>>1), byte (ql&1)*4
            size_t kvr = (size_t)(node0 + ml) * 128 + (wave == 2 ? 8 : 0);
#pragma unroll
            for (int t = 0; t < 4; ++t) {
                int pk = __builtin_amdgcn_cvt_pk_fp8_f32(acc[t][0], acc[t][1], 0, false);
                pk = __builtin_amdgcn_cvt_pk_fp8_f32(acc[t][2], acc[t][3], pk, true);
                size_t addr = kvr + (size_t)(t * 2 + (ql >> 1)) * 16 + (ql & 1) * 4;
                *(unsigned*)(kvO + addr) = (unsigned)pk;
            }
        }
    }
}

// gemm for layers 1-3 (512 blocks x 256 threads, measured-best)
__global__ __launch_bounds__(256) void gemm_mfma(
    const unsigned short* __restrict__ hbf, const unsigned short* __restrict__ Wt,
    const float* __restrict__ Bq, const float* __restrict__ Bk,
    const float* __restrict__ Bv, const float* __restrict__ Bs,
    int with_res,
    unsigned short* __restrict__ qO, unsigned char* __restrict__ kvO,
    unsigned short* __restrict__ sO, int ntiles) {
    gemm_phase(hbf, Wt, Bq, Bk, Bv, Bs, with_res, qO, kvO, sO, ntiles,
               blockIdx.x, gridDim.x, threadIdx.x & 63, threadIdx.x >> 6);
}

// ---- fused: blocks 0-127 scatter (col build), 128-255 layer-0 gemm ----
// Independent data -> concurrent use of all 256 CUs instead of half idle.
__global__ __launch_bounds__(1024) void scatter_gemm(
    const int* __restrict__ src, const int* __restrict__ dst,
    const unsigned* __restrict__ cb, const int* __restrict__ row_ptr,
    int* __restrict__ col, int E, int nbw,
    const unsigned short* __restrict__ hbf, const unsigned short* __restrict__ Wt,
    const float* __restrict__ Bq, const float* __restrict__ Bk,
    const float* __restrict__ Bv, const float* __restrict__ Bs,
    unsigned short* __restrict__ qO, unsigned char* __restrict__ kvO,
    unsigned short* __restrict__ sO, int ntiles) {
    if (blockIdx.x < NB_HIST) {
        // ---- scatter2 body (verbatim; chunk over NB_HIST blocks) ----
        extern __shared__ unsigned hist[];
        int blk = blockIdx.x;
        for (int w = threadIdx.x; w < nbw; w += blockDim.x) hist[w] = 0;
        __syncthreads();
        const unsigned* pref = cb + (size_t)blk * nbw;
        int chunk = (E + NB_HIST - 1) / NB_HIST;
        int beg = blk * chunk;
        int end = min(E, beg + chunk);
        for (int e = beg + (int)threadIdx.x; e < end; e += blockDim.x) {
            int d = dst[e];
            unsigned sh = (unsigned)(d & 1) * 16u;
            unsigned old = atomicAdd(&hist[d >> 1], 1u << sh);
            unsigned lr = (old >> sh) & 0xffffu;
            unsigned pre = (pref[d >> 1] >> sh) & 0xffffu;
            int slot = row_ptr[d] + (int)pre + (int)lr;
            __builtin_nontemporal_store(src[e] << 7, &col[slot]);
        }
    } else {
        // ---- layer-0 gemm: 4 virtual 4-wave blocks per 1024-thread block ----
        int vbid = (blockIdx.x - NB_HIST) * 4 + ((int)threadIdx.x >> 8);
        int lane = threadIdx.x & 63;
        int wave = ((int)threadIdx.x >> 6) & 3;
        gemm_phase(hbf, Wt, Bq, Bk, Bv, Bs, 0 /*layer0: no residual*/,
                   qO, kvO, sO, ntiles, vbid, (256 - NB_HIST) * 4, lane, wave);
    }
}

// ---------------- fused attention + LN ----------------
// One wave per dst node; 8 groups of 8 lanes; x2 volley (16 edge-slots).
// Byte-interleaved fp8 kv row: lane qi reads ONE uint4 (k-chunk | v-chunk).
// Logits carry log2(e) pre-scale -> p = exp2f(d). fp32 accum, LN+ReLU.
// Final layer (out != null) writes fp32 out only (hbf store is dead there).
#define EDGE_COMP(U) do {                                                      \
    f32x2 k0 = __builtin_amdgcn_cvt_pk_f32_fp8((U).x, false);                  \
    f32x2 k1 = __builtin_amdgcn_cvt_pk_f32_fp8((U).x, true);                   \
    f32x2 k2 = __builtin_amdgcn_cvt_pk_f32_fp8((U).y, false);                  \
    f32x2 k3 = __builtin_amdgcn_cvt_pk_f32_fp8((U).y, true);                   \
    float d = qf0 * k0[0];                                                     \
    d = fmaf(qf1, k0[1], d); d = fmaf(qf2, k1[0], d); d = fmaf(qf3, k1[1], d); \
    d = fmaf(qf4, k2[0], d); d = fmaf(qf5, k2[1], d); d = fmaf(qf6, k3[0], d); \
    d = fmaf(qf7, k3[1], d);                                                   \
    d += __shfl_xor(d, 1); d += __shfl_xor(d, 2); d += __shfl_xor(d, 4);       \
    float p = exp2f(d); ssum += p;                                             \
    f32x2 w0 = __builtin_amdgcn_cvt_pk_f32_fp8((U).z, false);                  \
    f32x2 w1 = __builtin_amdgcn_cvt_pk_f32_fp8((U).z, true);                   \
    f32x2 w2 = __builtin_amdgcn_cvt_pk_f32_fp8((U).w, false);                  \
    f32x2 w3 = __builtin_amdgcn_cvt_pk_f32_fp8((U).w, true);                   \
    aa.x = fmaf(w0[0], p, aa.x); aa.y = fmaf(w0[1], p, aa.y);                  \
    aa.z = fmaf(w1[0], p, aa.z); aa.w = fmaf(w1[1], p, aa.w);                  \
    ab.x = fmaf(w2[0], p, ab.x); ab.y = fmaf(w2[1], p, ab.y);                  \
    ab.z = fmaf(w3[0], p, ab.z); ab.w = fmaf(w3[1], p, ab.w);                  \
} while (0)

__global__ __launch_bounds__(256) void attn_agg_ln(
    const unsigned short* __restrict__ qh, const unsigned char* __restrict__ kv,
    const unsigned short* __restrict__ sk,
    const int* __restrict__ row_ptr, const int* __restrict__ col,
    const float* __restrict__ g, const float* __restrict__ b,
    float* __restrict__ out, unsigned short* __restrict__ hbf_out, int n) {
    int node = blockIdx.x * 4 + (threadIdx.x >> 6);
    int lane = threadIdx.x & 63;
    if (node >= n) return;
    int grp = lane >> 3;
    int qi = lane & 7;

    size_t ro = (size_t)node * DD + qi * 8;
    uint4 qu = *(const uint4*)(qh + ro);          // 8 f16, pre-scaled QSCALE
    uint4 su = *(const uint4*)(sk + ro);          // 8 f16 skip(+residual)
    int beg = row_ptr[node], end = row_ptr[node + 1];

    // unpack q to 8 f32 once (feeds fp8-k fma chain)
    h2 q0 = u2h2(qu.x), q1 = u2h2(qu.y), q2 = u2h2(qu.z), q3 = u2h2(qu.w);
    float qf0 = (float)q0[0], qf1 = (float)q0[1], qf2 = (float)q1[0], qf3 = (float)q1[1];
    float qf4 = (float)q2[0], qf5 = (float)q2[1], qf6 = (float)q3[0], qf7 = (float)q3[1];

    float ssum = 0.0f;
    float4 aa = {0.f, 0.f, 0.f, 0.f}, ab = {0.f, 0.f, 0.f, 0.f};

    int e = beg + grp;
    int cv0 = (e < end) ? col[e] : -1;
    int cv1 = (e + 8 < end) ? col[e + 8] : -1;
    for (int e0 = beg; e0 < end; e0 += 16) {
        bool a0 = cv0 >= 0, a1 = cv1 >= 0;
        uint4 u0, u1;
        if (a0) u0 = *(const uint4*)(kv + cv0 + qi * 16);   // k|v chunk, one load
        if (a1) u1 = *(const uint4*)(kv + cv1 + qi * 16);
        e += 16;
        cv0 = (e < end) ? col[e] : -1;
        cv1 = (e + 8 < end) ? col[e + 8] : -1;
        if (a0) EDGE_COMP(u0);
        if (a1) EDGE_COMP(u1);
    }

#pragma unroll
    for (int off = 8; off <= 32; off <<= 1) {
        ssum += __shfl_xor(ssum, off);
        aa.x += __shfl_xor(aa.x, off); aa.y += __shfl_xor(aa.y, off);
        aa.z += __shfl_xor(aa.z, off); aa.w += __shfl_xor(aa.w, off);
        ab.x += __shfl_xor(ab.x, off); ab.y += __shfl_xor(ab.y, off);
        ab.z += __shfl_xor(ab.z, off); ab.w += __shfl_xor(ab.w, off);
    }
    float inv = (end > beg) ? 1.0f / ssum : 0.0f;
    aa.x *= inv; aa.y *= inv; aa.z *= inv; aa.w *= inv;
    ab.x *= inv; ab.y *= inv; ab.z *= inv; ab.w *= inv;

    {   // + skip (+ residual), f16 -> f32
        h2 t0 = u2h2(su.x), t1 = u2h2(su.y), t2 = u2h2(su.z), t3 = u2h2(su.w);
        aa.x += (float)t0[0]; aa.y += (float)t0[1];
        aa.z += (float)t1[0]; aa.w += (float)t1[1];
        ab.x += (float)t2[0]; ab.y += (float)t2[1];
        ab.z += (float)t3[0]; ab.w += (float)t3[1];
    }

    float s1 = aa.x + aa.y + aa.z + aa.w + ab.x + ab.y + ab.z + ab.w;
    s1 += __shfl_xor(s1, 1);
    s1 += __shfl_xor(s1, 2);
    s1 += __shfl_xor(s1, 4);
    float mu = s1 * (1.0f / DD);
    float dx0 = aa.x - mu, dx1 = aa.y - mu, dx2 = aa.z - mu, dx3 = aa.w - mu;
    float dx4 = ab.x - mu, dx5 = ab.y - mu, dx6 = ab.z - mu, dx7 = ab.w - mu;
    float s2v = dx0 * dx0 + dx1 * dx1 + dx2 * dx2 + dx3 * dx3
              + dx4 * dx4 + dx5 * dx5 + dx6 * dx6 + dx7 * dx7;
    s2v += __shfl_xor(s2v, 1);
    s2v += __shfl_xor(s2v, 2);
    s2v += __shfl_xor(s2v, 4);
    float var = s2v * (1.0f / DD);
    float is = rsqrtf(var + 1e-5f);
    float4 g4a = *(const float4*)(g + qi * 8);
    float4 g4b = *(const float4*)(g + qi * 8 + 4);
    float4 b4a = *(const float4*)(b + qi * 8);
    float4 b4b = *(const float4*)(b + qi * 8 + 4);
    float4 ya, yb;
    ya.x = fmaxf(dx0 * is * g4a.x + b4a.x, 0.0f);
    ya.y = fmaxf(dx1 * is * g4a.y + b4a.y, 0.0f);
    ya.z = fmaxf(dx2 * is * g4a.z + b4a.z, 0.0f);
    ya.w = fmaxf(dx3 * is * g4a.w + b4a.w, 0.0f);
    yb.x = fmaxf(dx4 * is * g4b.x + b4b.x, 0.0f);
    yb.y = fmaxf(dx5 * is * g4b.y + b4b.y, 0.0f);
    yb.z = fmaxf(dx6 * is * g4b.z + b4b.z, 0.0f);
    yb.w = fmaxf(dx7 * is * g4b.w + b4b.w, 0.0f);
    if (grp == 0) {
        if (out) {                        // final layer: fp32 out only
            *(float4*)(out + ro) = ya;
            *(float4*)(out + ro + 4) = yb;
        } else {                          // layers 0-2: f16 carrier only
            uint4 hv;
            hv.x = pk2u(ya.x, ya.y);
            hv.y = pk2u(ya.z, ya.w);
            hv.z = pk2u(yb.x, yb.y);
            hv.w = pk2u(yb.z, yb.w);
            *(uint4*)(hbf_out + ro) = hv;
        }
    }
}

extern "C" void kernel_launch(void* const* d_in, const int* in_sizes, int n_in,
                              void* d_out, int out_size, void* d_ws, size_t ws_size,
                              hipStream_t stream) {
    const int D = DD;
    const float* x = (const float*)d_in[0];
    const int n = in_sizes[0] / D;       // 50000
    const int* ei = (const int*)d_in[1];
    const int E = in_sizes[1] / 2;       // 1e6
    const int* srcp = ei;
    const int* dstp = ei + E;
    const int nbw = (n + 1) / 2;         // bin-pair words (25000)

    static bool s_attr = false;
    if (!s_attr) {
        s_attr = true;
        (void)hipFuncSetAttribute((const void*)hist_prep,
                                  hipFuncAttributeMaxDynamicSharedMemorySize, 102400);
        (void)hipFuncSetAttribute((const void*)scatter_gemm,
                                  hipFuncAttributeMaxDynamicSharedMemorySize, 102400);
    }

    char* wsp = (char*)d_ws;
    auto take = [&](size_t bytes) {
        char* p = wsp;
        wsp += (bytes + 255) & ~(size_t)255;
        return (void*)p;
    };
    int* counts    = (int*)take((size_t)n * 4);
    int* row_ptr   = (int*)take((size_t)(n + 1) * 4);
    unsigned* cb   = (unsigned*)take((size_t)NB_HIST * nbw * 4);   // 12.8 MB
    int* col       = (int*)take((size_t)E * 4);
    int* localscan = (int*)take((size_t)n * 4);
    int* blockSums = (int*)take((size_t)1024 * 4);
    size_t fsz = (size_t)n * D * 4;
    unsigned short* qb  = (unsigned short*)take(fsz / 2);   // f16 q (pre-scaled)
    unsigned char* kvb  = (unsigned char*)take(fsz / 2);    // fp8 k|v rows: n*128B
    unsigned short* sb  = (unsigned short*)take(fsz / 2);   // f16 skip+residual
    unsigned short* hbf = (unsigned short*)take(fsz / 2);   // f16 h (layer carrier)
    unsigned short* Wt  = (unsigned short*)take((size_t)16 * 4096 * 2);

    // ---- CSR build + prep (no global atomics) ----
    int tb = 256;
    size_t ldsH = (size_t)nbw * 4;       // 100 KB
    int nbScan = (n + 1023) / 1024;      // 49
    hist_prep<<<NB_HIST, 1024, ldsH, stream>>>(
        dstp, cb, E, nbw,
        x, hbf, n * D,
        (const float*)d_in[2], (const float*)d_in[4], (const float*)d_in[6],
        (const float*)d_in[8], (const float*)d_in[12], (const float*)d_in[14],
        (const float*)d_in[16], (const float*)d_in[18], Wt);
    prefix_blk<<<(nbw + tb - 1) / tb, tb, 0, stream>>>(cb, counts, nbw, n);
    scan_local<<<nbScan, 1024, 0, stream>>>(counts, localscan, blockSums, n);
    emit_rowptr<<<(n + tb - 1) / tb, tb, 0, stream>>>(localscan, blockSums,
                                                      row_ptr, n, E, nbScan);

    // ---- fused scatter + layer-0 gemm (independent; 256 CUs busy) ----
    int ntiles = n / 16;                 // 3125
    int nba = (n + 3) / 4;
    scatter_gemm<<<NB_HIST * 2, 1024, ldsH, stream>>>(
        srcp, dstp, cb, row_ptr, col, E, nbw,
        hbf, Wt,
        (const float*)d_in[3], (const float*)d_in[5],
        (const float*)d_in[7], (const float*)d_in[9],
        qb, kvb, sb, ntiles);
    attn_agg_ln<<<nba, 256, 0, stream>>>(qb, kvb, sb, row_ptr, col,
                                         (const float*)d_in[10],
                                         (const float*)d_in[11],
                                         nullptr, hbf, n);

    // ---- layers 1-3 ----
    for (int layer = 1; layer < 4; ++layer) {
        int i = layer - 1;
        const float* bq_ = (const float*)d_in[13] + (size_t)i * D;
        const float* bk_ = (const float*)d_in[15] + (size_t)i * D;
        const float* bv_ = (const float*)d_in[17] + (size_t)i * D;
        const float* bs_ = (const float*)d_in[19] + (size_t)i * D;
        const float* g_  = (const float*)d_in[20] + (size_t)i * D;
        const float* b_  = (const float*)d_in[21] + (size_t)i * D;
        gemm_mfma<<<512, 256, 0, stream>>>(hbf, Wt + (size_t)layer * 4 * 4096,
                                           bq_, bk_, bv_, bs_, 1,
                                           qb, kvb, sb, ntiles);
        attn_agg_ln<<<nba, 256, 0, stream>>>(qb, kvb, sb, row_ptr, col, g_, b_,
                                             layer == 3 ? (float*)d_out : nullptr,
                                             hbf, n);
    }
}